// Round 1
// baseline (1691.280 us; speedup 1.0000x reference)
//
#include <hip/hip_runtime.h>
#include <hip/hip_bf16.h>

// Problem constants
#define B_  64
#define C_  64
#define T_  300
#define V_  25
#define O_  128
#define NADJ 8
#define TT  10          // time steps per k_main block
#define NT  (T_/TT)     // 30 tiles
#define TV  (T_*V_)     // 7500 per (b,c) row
#define BTV (B_*T_*V_)  // 480000 count for BN stats

// ws layout (float offsets)
#define WS_APOW   0        // 8*625, padded to 5120
#define WS_WT     5120     // Wt[c][o] stacked: 64*256 = 16384
#define WS_PSUM   21504    // [128][64]
#define WS_PSQ    29696    // [128][64]
#define WS_SCALE  37888    // [128]
#define WS_SHIFT  38016    // [128]

// ---------------- K1: A powers + transposed stacked weights ----------------
__global__ __launch_bounds__(256) void k_pre(const float* __restrict__ A,
                                             const float* __restrict__ W,
                                             const float* __restrict__ Wr,
                                             float* __restrict__ apow,
                                             float* __restrict__ wt) {
    __shared__ float P[2][625];
    int tid = threadIdx.x;
    for (int p = tid; p < 625; p += 256) { P[0][p] = A[p]; apow[p] = A[p]; }
    __syncthreads();
    int cur = 0;
    for (int i = 1; i < NADJ; i++) {
        for (int p = tid; p < 625; p += 256) {
            int r = p / 25, c2 = p - r * 25;
            float s = 0.f;
            #pragma unroll 5
            for (int j = 0; j < 25; j++) s = fmaf(P[cur][r*25 + j], A[j*25 + c2], s);
            P[cur ^ 1][p] = s;
            apow[i*625 + p] = s;
        }
        __syncthreads();
        cur ^= 1;
    }
    // Wt[c][o]: o<128 -> Wall[o][c] (W flat [128][64]); o>=128 -> Wr[o-128][c]
    for (int idx = tid; idx < 64 * 256; idx += 256) {
        int c = idx >> 8, o = idx & 255;
        wt[idx] = (o < 128) ? W[o*64 + c] : Wr[(o - 128)*64 + c];
    }
}

// ---------------- K2: fused graph-conv + 1x1 convs + residual (pre-BN) ------
// block: 256 threads (250 active = (t in 0..9, k in 0..24)); grid (64, 30)
#define CONV_CC(CC, GC, XC)                                                    \
  {                                                                            \
    const float* wA = wbase + (CC) * 256;                                      \
    _Pragma("unroll")                                                          \
    for (int op = 0; op < 16; op++)                                            \
        acc[op] = fmaf(wA[op], (GC), fmaf(wA[128 + op], (XC), acc[op]));       \
  }

#define CONV_BRANCH(G, IBR)                                                    \
  {                                                                            \
    const int o0 = (IBR) * 16;                                                 \
    float acc[16];                                                             \
    _Pragma("unroll")                                                          \
    for (int op = 0; op < 16; op++) acc[op] = br[o0 + op];                     \
    _Pragma("unroll")                                                          \
    for (int cg = 0; cg < 16; cg++) {                                          \
      float4 g = G[cg];                                                        \
      float4 xv = xk[cg ^ swk];                                                \
      const float* wbase = wt + (cg * 4) * 256 + o0;                           \
      CONV_CC(0, g.x, xv.x)                                                    \
      CONV_CC(1, g.y, xv.y)                                                    \
      CONV_CC(2, g.z, xv.z)                                                    \
      CONV_CC(3, g.w, xv.w)                                                    \
    }                                                                          \
    size_t ob = ((size_t)(b * 128 + o0) * 300 + (t0 + t)) * 25 + k;            \
    _Pragma("unroll")                                                          \
    for (int op = 0; op < 16; op++) out[ob + (size_t)op * 7500] = acc[op];     \
  }

__global__ __launch_bounds__(256) void k_main(const float* __restrict__ x,
                                              const float* __restrict__ apow,
                                              const float* __restrict__ wt,
                                              const float* __restrict__ br,
                                              float* __restrict__ out) {
    __shared__ float Xs[250 * 64];   // [t*25+v][c] with XOR-swizzled float4 columns
    const int b = blockIdx.x, tile = blockIdx.y;
    const int t0 = tile * TT;
    const int tid = threadIdx.x;

    const float* xb = x + (size_t)b * (C_ * TV) + t0 * V_;
    for (int idx = tid; idx < 64 * 250; idx += 256) {
        int c = idx / 250, r = idx - c * 250;
        int c4 = c >> 2, cl = c & 3;
        int cs = ((c4 ^ (r & 7)) << 2) | cl;    // swizzle float4 slot by row
        Xs[r * 64 + cs] = xb[c * TV + r];
    }
    __syncthreads();

    if (tid >= 250) return;
    const int t = tid / 25, k = tid - t * 25;
    const int rk = t * 25 + k;
    const int swk = rk & 7;
    const float4* xk = (const float4*)(Xs + rk * 64);

    #pragma unroll 1
    for (int p = 0; p < 4; p++) {
        float4 G0[16], G1[16];
        #pragma unroll
        for (int cg = 0; cg < 16; cg++) {
            G0[cg] = make_float4(0.f, 0.f, 0.f, 0.f);
            G1[cg] = make_float4(0.f, 0.f, 0.f, 0.f);
        }
        const float* A0 = apow + (2 * p) * 625 + k;
        #pragma unroll 5
        for (int j = 0; j < 25; j++) {
            float a0 = A0[j * 25];
            float a1 = A0[625 + j * 25];
            int rj = t * 25 + j;
            const float4* xr = (const float4*)(Xs + rj * 64);
            int sw = rj & 7;
            #pragma unroll
            for (int cg = 0; cg < 16; cg++) {
                float4 xv = xr[cg ^ sw];
                G0[cg].x = fmaf(xv.x, a0, G0[cg].x);
                G0[cg].y = fmaf(xv.y, a0, G0[cg].y);
                G0[cg].z = fmaf(xv.z, a0, G0[cg].z);
                G0[cg].w = fmaf(xv.w, a0, G0[cg].w);
                G1[cg].x = fmaf(xv.x, a1, G1[cg].x);
                G1[cg].y = fmaf(xv.y, a1, G1[cg].y);
                G1[cg].z = fmaf(xv.z, a1, G1[cg].z);
                G1[cg].w = fmaf(xv.w, a1, G1[cg].w);
            }
        }
        CONV_BRANCH(G0, 2 * p)
        CONV_BRANCH(G1, 2 * p + 1)
    }
}

// ---------------- K3: per-(b,o) partial sums (deterministic) ----------------
__global__ __launch_bounds__(256) void k_stats(const float* __restrict__ out,
                                               float* __restrict__ psum,
                                               float* __restrict__ psq) {
    const int bo = blockIdx.x;            // b*128 + o
    const int b = bo >> 7, o = bo & 127;
    const float4* p = (const float4*)(out + (size_t)bo * TV);
    float s = 0.f, q = 0.f;
    for (int i = threadIdx.x; i < TV / 4; i += 256) {
        float4 v = p[i];
        s += v.x + v.y + v.z + v.w;
        q += v.x * v.x + v.y * v.y + v.z * v.z + v.w * v.w;
    }
    #pragma unroll
    for (int m = 1; m < 64; m <<= 1) { s += __shfl_xor(s, m); q += __shfl_xor(q, m); }
    __shared__ float ls[4], lq[4];
    int w = threadIdx.x >> 6;
    if ((threadIdx.x & 63) == 0) { ls[w] = s; lq[w] = q; }
    __syncthreads();
    if (threadIdx.x == 0) {
        psum[o * 64 + b] = ls[0] + ls[1] + ls[2] + ls[3];
        psq[o * 64 + b]  = lq[0] + lq[1] + lq[2] + lq[3];
    }
}

// ---------------- K4: finalize BN scale/shift ------------------------------
__global__ void k_finalize(const float* __restrict__ psum, const float* __restrict__ psq,
                           const float* __restrict__ gamma, const float* __restrict__ beta,
                           float* __restrict__ scale, float* __restrict__ shift) {
    int o = threadIdx.x;
    if (o >= 128) return;
    float S = 0.f, Q = 0.f;
    for (int j = 0; j < 64; j++) { S += psum[o * 64 + j]; Q += psq[o * 64 + j]; }
    float inv = 1.f / (float)BTV;
    float mean = S * inv;
    float var = Q * inv - mean * mean;
    float sc = gamma[o] / sqrtf(var + 1e-5f);
    scale[o] = sc;
    shift[o] = beta[o] - mean * sc;
}

// ---------------- K5: normalize + ReLU in place ----------------------------
__global__ __launch_bounds__(256) void k_norm(float* __restrict__ out,
                                              const float* __restrict__ scale,
                                              const float* __restrict__ shift) {
    unsigned int f = blockIdx.x * 256u + threadIdx.x;   // float4 index
    int o = (int)((f / 1875u) & 127u);                  // 7500/4 per (b,o)
    float sc = scale[o], sh = shift[o];
    float4* p = (float4*)out;
    float4 v = p[f];
    v.x = fmaxf(fmaf(v.x, sc, sh), 0.f);
    v.y = fmaxf(fmaf(v.y, sc, sh), 0.f);
    v.z = fmaxf(fmaf(v.z, sc, sh), 0.f);
    v.w = fmaxf(fmaf(v.w, sc, sh), 0.f);
    p[f] = v;
}

extern "C" void kernel_launch(void* const* d_in, const int* in_sizes, int n_in,
                              void* d_out, int out_size, void* d_ws, size_t ws_size,
                              hipStream_t stream) {
    const float* x     = (const float*)d_in[0];
    const float* A     = (const float*)d_in[1];
    const float* W     = (const float*)d_in[2];
    const float* Wr    = (const float*)d_in[3];
    const float* br    = (const float*)d_in[4];
    const float* gamma = (const float*)d_in[5];
    const float* beta  = (const float*)d_in[6];
    float* out = (float*)d_out;
    float* ws  = (float*)d_ws;

    float* apow  = ws + WS_APOW;
    float* wt    = ws + WS_WT;
    float* psum  = ws + WS_PSUM;
    float* psq   = ws + WS_PSQ;
    float* scale = ws + WS_SCALE;
    float* shift = ws + WS_SHIFT;

    k_pre<<<1, 256, 0, stream>>>(A, W, Wr, apow, wt);
    dim3 g2(B_, NT);
    k_main<<<g2, 256, 0, stream>>>(x, apow, wt, br, out);
    k_stats<<<B_ * O_, 256, 0, stream>>>(out, psum, psq);
    k_finalize<<<1, 128, 0, stream>>>(psum, psq, gamma, beta, scale, shift);
    k_norm<<<(out_size / 4) / 256, 256, 0, stream>>>(out, scale, shift);
}

// Round 2
// 511.008 us; speedup vs baseline: 3.3097x; 3.3097x over previous
//
#include <hip/hip_runtime.h>
#include <hip/hip_bf16.h>

// Problem constants
#define B_  64
#define C_  64
#define T_  300
#define V_  25
#define O_  128
#define NADJ 8
#define TT  10
#define NT  (T_/TT)
#define TV  (T_*V_)     // 7500
#define BTV (B_*T_*V_)  // 480000

// ---- GEMM view: M=19200 rows (b,t), N=3200 cols (o,k), K=1600 (c,j) ----
#define GM 19200
#define GN 3200
#define GK 1600

typedef __bf16 bf16x8 __attribute__((ext_vector_type(8)));
typedef float f32x4 __attribute__((ext_vector_type(4)));

// ---- new ws layout (byte offsets) ----
#define WSB_X2    0u           // 19200*1600 bf16 = 61,440,000 B
#define WSB_MT    61440000u    // 3200*1600 bf16  = 10,240,000 B
#define WSB_APW   71680000u    // 8*625 f32 = 20,000 B
#define WSB_PSUM  71700000u    // 128*64 f32 = 32,768 B
#define WSB_PSQ   71732768u
#define WSB_SCALE 71765536u    // 128 f32
#define WSB_SHIFT 71766048u
#define WS_NEED   71766560u

static __device__ __forceinline__ unsigned short f2bf(float f) {
    unsigned int u = __float_as_uint(f);
    unsigned int r = (u + 0x7fffu + ((u >> 16) & 1u)) >> 16;
    return (unsigned short)r;
}

// =================== NEW PATH ===================

// A^1..A^8 into ws
__global__ __launch_bounds__(256) void k_apow(const float* __restrict__ A,
                                              float* __restrict__ apow) {
    __shared__ float P[2][625];
    int tid = threadIdx.x;
    for (int p = tid; p < 625; p += 256) { P[0][p] = A[p]; apow[p] = A[p]; }
    __syncthreads();
    int cur = 0;
    for (int i = 1; i < NADJ; i++) {
        for (int p = tid; p < 625; p += 256) {
            int r = p / 25, c2 = p - r * 25;
            float s = 0.f;
            #pragma unroll 5
            for (int j = 0; j < 25; j++) s = fmaf(P[cur][r*25 + j], A[j*25 + c2], s);
            P[cur ^ 1][p] = s;
            apow[i*625 + p] = s;
        }
        __syncthreads();
        cur ^= 1;
    }
}

// Mt[n=(o*25+k)][kk=(c*25+j)] bf16 = W[o,c]*A^{i+1}[j,k] + Wr[o,c]*(j==k)
__global__ __launch_bounds__(256) void k_prep(const float* __restrict__ W,
                                              const float* __restrict__ Wr,
                                              const float* __restrict__ apow,
                                              unsigned short* __restrict__ Mt) {
    const int n = blockIdx.x;            // 0..3199
    const int o = n / 25, kv = n - o * 25;
    const int i = o >> 4;
    const float* Wo  = W  + o * 64;
    const float* Wro = Wr + o * 64;
    const float* Ai  = apow + i * 625;
    const int tid = threadIdx.x;
    if (tid >= 200) return;
    const int kk0 = tid * 8;
    unsigned short v[8];
    #pragma unroll
    for (int e = 0; e < 8; e++) {
        int kk = kk0 + e;
        int c = kk / 25, j = kk - c * 25;
        float val = Wo[c] * Ai[j * 25 + kv];
        if (j == kv) val += Wro[c];
        v[e] = f2bf(val);
    }
    *(uint4*)(Mt + (size_t)n * GK + kk0) = *(uint4*)v;
}

// x[b,c,t,v] f32 -> X2[(b*300+t)][(c*25+v)] bf16   (c<->t swap, LDS tiled)
__global__ __launch_bounds__(256) void k_xpose(const float* __restrict__ x,
                                               unsigned short* __restrict__ X2) {
    __shared__ unsigned short Ls[100 * 200];   // [tt][ci*25+v], 40 KB
    const int b = blockIdx.z, t0 = blockIdx.y * 100, c0 = blockIdx.x * 8;
    const int tid = threadIdx.x;
    // read 8 c-slices of 100 t x 25 v (2500 floats each, float4-aligned)
    for (int idx = tid; idx < 5000; idx += 256) {
        int ci = idx / 625, e = idx - ci * 625;
        const float4* src = (const float4*)(x + ((size_t)(b * 64 + c0 + ci)) * TV + t0 * 25);
        float4 f = src[e];
        int p = e * 4;
        float vals[4] = { f.x, f.y, f.z, f.w };
        #pragma unroll
        for (int q = 0; q < 4; q++) {
            int pp = p + q;
            int tt = pp / 25, vv = pp - tt * 25;
            Ls[tt * 200 + ci * 25 + vv] = f2bf(vals[q]);
        }
    }
    __syncthreads();
    // write rows: 100 rows x 25 uint4 (400B per row, 16B aligned: c0*50 % 16 == 0)
    for (int i = tid; i < 2500; i += 256) {
        int tt = i / 25, w = i - tt * 25;
        uint4 d = *(uint4*)(Ls + tt * 200 + w * 8);
        *(uint4*)(X2 + ((size_t)(b * 300 + t0 + tt)) * GK + c0 * 25 + w * 8) = d;
    }
}

// 128x128 bf16 MFMA GEMM (m97 structure: BK=32, global_load_lds, dbuf LDS)
__global__ __launch_bounds__(256) void k_gemm(const unsigned short* __restrict__ X2,
                                              const unsigned short* __restrict__ Mt,
                                              float* __restrict__ out) {
    __shared__ __align__(16) unsigned short lds[2][8192];  // [buf][A 4096 | B 4096]
    const int ctile = blockIdx.x, rtile = blockIdx.y;
    const int tid = threadIdx.x, wv = tid >> 6, ln = tid & 63;
    const int wr = wv >> 1, wc = wv & 1;

    // per-lane staging source bases (row = base + q*16 + (ln>>2); 16B chunk (ln&3))
    const char* Ab = (const char*)X2 + (size_t)(rtile * 128 + (ln >> 2)) * 3200 + (ln & 3) * 16;
    const char* Bb = (const char*)Mt + (size_t)(ctile * 128 + (ln >> 2)) * 3200 + (ln & 3) * 16;

    f32x4 acc[4][4] = {};

    #define STAGE(buf, kt)                                                              \
    {                                                                                   \
        unsigned int kb = (unsigned int)(kt) * 64u;                                     \
        _Pragma("unroll")                                                               \
        for (int s = 0; s < 2; s++) {                                                   \
            int q = wv + s * 4;                                                         \
            __builtin_amdgcn_global_load_lds(                                           \
                (const __attribute__((address_space(1))) void*)(Ab + (size_t)q * 51200 + kb), \
                (__attribute__((address_space(3))) void*)(&lds[buf][0] + q * 512), 16, 0, 0); \
            __builtin_amdgcn_global_load_lds(                                           \
                (const __attribute__((address_space(1))) void*)(Bb + (size_t)q * 51200 + kb), \
                (__attribute__((address_space(3))) void*)(&lds[buf][4096] + q * 512), 16, 0, 0); \
        }                                                                               \
    }

    STAGE(0, 0)
    __syncthreads();
    int cur = 0;
    for (int kt = 0; kt < GK / 32; kt++) {
        if (kt < GK / 32 - 1) {
            if (cur == 0) STAGE(1, kt + 1) else STAGE(0, kt + 1)
        }
        const unsigned short* Al = &lds[cur][0];
        const unsigned short* Bl = &lds[cur][4096];
        bf16x8 af[4], bfv[4];
        #pragma unroll
        for (int i = 0; i < 4; i++) {
            af[i]  = *(const bf16x8*)(Al + (wr * 64 + i * 16 + (ln & 15)) * 32 + (ln >> 4) * 8);
            bfv[i] = *(const bf16x8*)(Bl + (wc * 64 + i * 16 + (ln & 15)) * 32 + (ln >> 4) * 8);
        }
        #pragma unroll
        for (int mi = 0; mi < 4; mi++)
            #pragma unroll
            for (int ni = 0; ni < 4; ni++)
                acc[mi][ni] = __builtin_amdgcn_mfma_f32_16x16x32_bf16(af[mi], bfv[ni], acc[mi][ni], 0, 0, 0);
        __syncthreads();
        cur ^= 1;
    }

    // epilogue: D row=(b,t) col=(o,k) -> out[b,o,t,k]
    const int r0 = rtile * 128 + wr * 64 + (ln >> 4) * 4;
    const int n0 = ctile * 128 + wc * 64 + (ln & 15);
    #pragma unroll
    for (int ni = 0; ni < 4; ni++) {
        int col = n0 + ni * 16;
        int o = col / 25, kv = col - o * 25;
        #pragma unroll
        for (int mi = 0; mi < 4; mi++) {
            #pragma unroll
            for (int r = 0; r < 4; r++) {
                int row = r0 + mi * 16 + r;
                int b = row / 300, t = row - b * 300;
                out[(((size_t)(b * 128 + o)) * 300 + t) * 25 + kv] = acc[mi][ni][r];
            }
        }
    }
}

// =================== FALLBACK (round-1) PATH ===================

#define WS_APOW   0
#define WS_WT     5120
#define WS_PSUM   21504
#define WS_PSQ    29696
#define WS_SCALE  37888
#define WS_SHIFT  38016

__global__ __launch_bounds__(256) void k_pre(const float* __restrict__ A,
                                             const float* __restrict__ W,
                                             const float* __restrict__ Wr,
                                             float* __restrict__ apow,
                                             float* __restrict__ wt) {
    __shared__ float P[2][625];
    int tid = threadIdx.x;
    for (int p = tid; p < 625; p += 256) { P[0][p] = A[p]; apow[p] = A[p]; }
    __syncthreads();
    int cur = 0;
    for (int i = 1; i < NADJ; i++) {
        for (int p = tid; p < 625; p += 256) {
            int r = p / 25, c2 = p - r * 25;
            float s = 0.f;
            #pragma unroll 5
            for (int j = 0; j < 25; j++) s = fmaf(P[cur][r*25 + j], A[j*25 + c2], s);
            P[cur ^ 1][p] = s;
            apow[i*625 + p] = s;
        }
        __syncthreads();
        cur ^= 1;
    }
    for (int idx = tid; idx < 64 * 256; idx += 256) {
        int c = idx >> 8, o = idx & 255;
        wt[idx] = (o < 128) ? W[o*64 + c] : Wr[(o - 128)*64 + c];
    }
}

#define CONV_CC(CC, GC, XC)                                                    \
  {                                                                            \
    const float* wA = wbase + (CC) * 256;                                      \
    _Pragma("unroll")                                                          \
    for (int op = 0; op < 16; op++)                                            \
        acc[op] = fmaf(wA[op], (GC), fmaf(wA[128 + op], (XC), acc[op]));       \
  }

#define CONV_BRANCH(G, IBR)                                                    \
  {                                                                            \
    const int o0 = (IBR) * 16;                                                 \
    float acc[16];                                                             \
    _Pragma("unroll")                                                          \
    for (int op = 0; op < 16; op++) acc[op] = br[o0 + op];                     \
    _Pragma("unroll")                                                          \
    for (int cg = 0; cg < 16; cg++) {                                          \
      float4 g = G[cg];                                                        \
      float4 xv = xk[cg ^ swk];                                                \
      const float* wbase = wt + (cg * 4) * 256 + o0;                           \
      CONV_CC(0, g.x, xv.x)                                                    \
      CONV_CC(1, g.y, xv.y)                                                    \
      CONV_CC(2, g.z, xv.z)                                                    \
      CONV_CC(3, g.w, xv.w)                                                    \
    }                                                                          \
    size_t ob = ((size_t)(b * 128 + o0) * 300 + (t0 + t)) * 25 + k;            \
    _Pragma("unroll")                                                          \
    for (int op = 0; op < 16; op++) out[ob + (size_t)op * 7500] = acc[op];     \
  }

__global__ __launch_bounds__(256) void k_main(const float* __restrict__ x,
                                              const float* __restrict__ apow,
                                              const float* __restrict__ wt,
                                              const float* __restrict__ br,
                                              float* __restrict__ out) {
    __shared__ float Xs[250 * 64];
    const int b = blockIdx.x, tile = blockIdx.y;
    const int t0 = tile * TT;
    const int tid = threadIdx.x;

    const float* xb = x + (size_t)b * (C_ * TV) + t0 * V_;
    for (int idx = tid; idx < 64 * 250; idx += 256) {
        int c = idx / 250, r = idx - c * 250;
        int c4 = c >> 2, cl = c & 3;
        int cs = ((c4 ^ (r & 7)) << 2) | cl;
        Xs[r * 64 + cs] = xb[c * TV + r];
    }
    __syncthreads();

    if (tid >= 250) return;
    const int t = tid / 25, k = tid - t * 25;
    const int rk = t * 25 + k;
    const int swk = rk & 7;
    const float4* xk = (const float4*)(Xs + rk * 64);

    #pragma unroll 1
    for (int p = 0; p < 4; p++) {
        float4 G0[16], G1[16];
        #pragma unroll
        for (int cg = 0; cg < 16; cg++) {
            G0[cg] = make_float4(0.f, 0.f, 0.f, 0.f);
            G1[cg] = make_float4(0.f, 0.f, 0.f, 0.f);
        }
        const float* A0 = apow + (2 * p) * 625 + k;
        #pragma unroll 5
        for (int j = 0; j < 25; j++) {
            float a0 = A0[j * 25];
            float a1 = A0[625 + j * 25];
            int rj = t * 25 + j;
            const float4* xr = (const float4*)(Xs + rj * 64);
            int sw = rj & 7;
            #pragma unroll
            for (int cg = 0; cg < 16; cg++) {
                float4 xv = xr[cg ^ sw];
                G0[cg].x = fmaf(xv.x, a0, G0[cg].x);
                G0[cg].y = fmaf(xv.y, a0, G0[cg].y);
                G0[cg].z = fmaf(xv.z, a0, G0[cg].z);
                G0[cg].w = fmaf(xv.w, a0, G0[cg].w);
                G1[cg].x = fmaf(xv.x, a1, G1[cg].x);
                G1[cg].y = fmaf(xv.y, a1, G1[cg].y);
                G1[cg].z = fmaf(xv.z, a1, G1[cg].z);
                G1[cg].w = fmaf(xv.w, a1, G1[cg].w);
            }
        }
        CONV_BRANCH(G0, 2 * p)
        CONV_BRANCH(G1, 2 * p + 1)
    }
}

// =================== SHARED BN KERNELS ===================

__global__ __launch_bounds__(256) void k_stats(const float* __restrict__ out,
                                               float* __restrict__ psum,
                                               float* __restrict__ psq) {
    const int bo = blockIdx.x;
    const int b = bo >> 7, o = bo & 127;
    const float4* p = (const float4*)(out + (size_t)bo * TV);
    float s = 0.f, q = 0.f;
    for (int i = threadIdx.x; i < TV / 4; i += 256) {
        float4 v = p[i];
        s += v.x + v.y + v.z + v.w;
        q += v.x * v.x + v.y * v.y + v.z * v.z + v.w * v.w;
    }
    #pragma unroll
    for (int m = 1; m < 64; m <<= 1) { s += __shfl_xor(s, m); q += __shfl_xor(q, m); }
    __shared__ float ls[4], lq[4];
    int w = threadIdx.x >> 6;
    if ((threadIdx.x & 63) == 0) { ls[w] = s; lq[w] = q; }
    __syncthreads();
    if (threadIdx.x == 0) {
        psum[o * 64 + b] = ls[0] + ls[1] + ls[2] + ls[3];
        psq[o * 64 + b]  = lq[0] + lq[1] + lq[2] + lq[3];
    }
}

__global__ void k_finalize(const float* __restrict__ psum, const float* __restrict__ psq,
                           const float* __restrict__ gamma, const float* __restrict__ beta,
                           float* __restrict__ scale, float* __restrict__ shift) {
    int o = threadIdx.x;
    if (o >= 128) return;
    float S = 0.f, Q = 0.f;
    for (int j = 0; j < 64; j++) { S += psum[o * 64 + j]; Q += psq[o * 64 + j]; }
    float inv = 1.f / (float)BTV;
    float mean = S * inv;
    float var = Q * inv - mean * mean;
    float sc = gamma[o] / sqrtf(var + 1e-5f);
    scale[o] = sc;
    shift[o] = beta[o] - mean * sc;
}

__global__ __launch_bounds__(256) void k_norm(float* __restrict__ out,
                                              const float* __restrict__ scale,
                                              const float* __restrict__ shift) {
    unsigned int f = blockIdx.x * 256u + threadIdx.x;
    int o = (int)((f / 1875u) & 127u);
    float sc = scale[o], sh = shift[o];
    float4* p = (float4*)out;
    float4 v = p[f];
    v.x = fmaxf(fmaf(v.x, sc, sh), 0.f);
    v.y = fmaxf(fmaf(v.y, sc, sh), 0.f);
    v.z = fmaxf(fmaf(v.z, sc, sh), 0.f);
    v.w = fmaxf(fmaf(v.w, sc, sh), 0.f);
    p[f] = v;
}

extern "C" void kernel_launch(void* const* d_in, const int* in_sizes, int n_in,
                              void* d_out, int out_size, void* d_ws, size_t ws_size,
                              hipStream_t stream) {
    const float* x     = (const float*)d_in[0];
    const float* A     = (const float*)d_in[1];
    const float* W     = (const float*)d_in[2];
    const float* Wr    = (const float*)d_in[3];
    const float* br    = (const float*)d_in[4];
    const float* gamma = (const float*)d_in[5];
    const float* beta  = (const float*)d_in[6];
    float* out = (float*)d_out;
    char* wsb  = (char*)d_ws;

    if (ws_size >= (size_t)WS_NEED) {
        unsigned short* X2 = (unsigned short*)(wsb + WSB_X2);
        unsigned short* Mt = (unsigned short*)(wsb + WSB_MT);
        float* apow  = (float*)(wsb + WSB_APW);
        float* psum  = (float*)(wsb + WSB_PSUM);
        float* psq   = (float*)(wsb + WSB_PSQ);
        float* scale = (float*)(wsb + WSB_SCALE);
        float* shift = (float*)(wsb + WSB_SHIFT);

        k_apow<<<1, 256, 0, stream>>>(A, apow);
        k_xpose<<<dim3(8, 3, 64), 256, 0, stream>>>(x, X2);
        k_prep<<<GN, 256, 0, stream>>>(W, Wr, apow, Mt);
        k_gemm<<<dim3(GN / 128, GM / 128), 256, 0, stream>>>(X2, Mt, out);
        k_stats<<<B_ * O_, 256, 0, stream>>>(out, psum, psq);
        k_finalize<<<1, 128, 0, stream>>>(psum, psq, gamma, beta, scale, shift);
        k_norm<<<(out_size / 4) / 256, 256, 0, stream>>>(out, scale, shift);
    } else {
        float* ws = (float*)d_ws;
        float* apow  = ws + WS_APOW;
        float* wt    = ws + WS_WT;
        float* psum  = ws + WS_PSUM;
        float* psq   = ws + WS_PSQ;
        float* scale = ws + WS_SCALE;
        float* shift = ws + WS_SHIFT;

        k_pre<<<1, 256, 0, stream>>>(A, W, Wr, apow, wt);
        k_main<<<dim3(B_, NT), 256, 0, stream>>>(x, apow, wt, br, out);
        k_stats<<<B_ * O_, 256, 0, stream>>>(out, psum, psq);
        k_finalize<<<1, 128, 0, stream>>>(psum, psq, gamma, beta, scale, shift);
        k_norm<<<(out_size / 4) / 256, 256, 0, stream>>>(out, scale, shift);
    }
}

// Round 3
// 481.574 us; speedup vs baseline: 3.5120x; 1.0611x over previous
//
#include <hip/hip_runtime.h>
#include <hip/hip_bf16.h>

// Problem constants
#define B_  64
#define C_  64
#define T_  300
#define V_  25
#define O_  128
#define NADJ 8
#define TV  (T_*V_)     // 7500
#define BTV (B_*T_*V_)  // 480000

// GEMM view: M=19200 rows (b,t), N=3200 cols (o,k), K=1600 (c,j)
#define GM 19200
#define GN 3200
#define GK 1600

typedef __bf16 bf16x8 __attribute__((ext_vector_type(8)));
typedef float f32x4 __attribute__((ext_vector_type(4)));

// ---- FULL ws layout (byte offsets) ----
#define WSB_X2    0ull          // 19200*1600*2 = 61,440,000
#define WSB_MT    61440000ull   // 3200*1600*2  = 10,240,000
#define WSB_APW   71680000ull   // 8*625*4 = 20,000
#define WSB_Y     71700000ull   // 3200*19200*2 = 122,880,000
#define WSB_PSC   194580000ull  // 3200*150*4 = 1,920,000
#define WSB_PSQ   196500000ull
#define WSB_SCL   198420000ull  // 128*4
#define WSB_SFT   198420512ull
#define WS_NEED_FULL 198421024ull

// ---- MID ws layout (no Y) ----
#define WSM_PSC   71700000ull
#define WSM_PSQ   73620000ull
#define WSM_SCL   75540000ull
#define WSM_SFT   75540512ull
#define WS_NEED_MID 75541024ull

// ---- legacy (round-2) float offsets ----
#define WS_PSUM   21504
#define WS_PSQ2   29696
#define WS_SCALE  37888
#define WS_SHIFT  38016

static __device__ __forceinline__ unsigned short f2bf(float f) {
    unsigned int u = __float_as_uint(f);
    unsigned int r = (u + 0x7fffu + ((u >> 16) & 1u)) >> 16;
    return (unsigned short)r;
}
static __device__ __forceinline__ unsigned int pk2bf(float a, float b) {
    return (unsigned int)f2bf(a) | ((unsigned int)f2bf(b) << 16);
}
static __device__ __forceinline__ float bf2f(unsigned short u) {
    return __uint_as_float(((unsigned int)u) << 16);
}

// ---------------- A powers ----------------
__global__ __launch_bounds__(256) void k_apow(const float* __restrict__ A,
                                              float* __restrict__ apow) {
    __shared__ float P[2][625];
    int tid = threadIdx.x;
    for (int p = tid; p < 625; p += 256) { P[0][p] = A[p]; apow[p] = A[p]; }
    __syncthreads();
    int cur = 0;
    for (int i = 1; i < NADJ; i++) {
        for (int p = tid; p < 625; p += 256) {
            int r = p / 25, c2 = p - r * 25;
            float s = 0.f;
            #pragma unroll 5
            for (int j = 0; j < 25; j++) s = fmaf(P[cur][r*25 + j], A[j*25 + c2], s);
            P[cur ^ 1][p] = s;
            apow[i*625 + p] = s;
        }
        __syncthreads();
        cur ^= 1;
    }
}

// Mt[n=(o*25+k)][kk=(c*25+j)] bf16 = W[o,c]*A^{i+1}[j,k] + Wr[o,c]*(j==k)
__global__ __launch_bounds__(256) void k_prep(const float* __restrict__ W,
                                              const float* __restrict__ Wr,
                                              const float* __restrict__ apow,
                                              unsigned short* __restrict__ Mt) {
    const int n = blockIdx.x;
    const int o = n / 25, kv = n - o * 25;
    const int i = o >> 4;
    const float* Wo  = W  + o * 64;
    const float* Wro = Wr + o * 64;
    const float* Ai  = apow + i * 625;
    const int tid = threadIdx.x;
    if (tid >= 200) return;
    const int kk0 = tid * 8;
    unsigned short v[8];
    #pragma unroll
    for (int e = 0; e < 8; e++) {
        int kk = kk0 + e;
        int c = kk / 25, j = kk - c * 25;
        float val = Wo[c] * Ai[j * 25 + kv];
        if (j == kv) val += Wro[c];
        v[e] = f2bf(val);
    }
    *(uint4*)(Mt + (size_t)n * GK + kk0) = *(uint4*)v;
}

// x[b,c,t,v] f32 -> X2[(b*300+t)][(c*25+v)] bf16
__global__ __launch_bounds__(256) void k_xpose(const float* __restrict__ x,
                                               unsigned short* __restrict__ X2) {
    __shared__ unsigned short Ls[100 * 200];
    const int b = blockIdx.z, t0 = blockIdx.y * 100, c0 = blockIdx.x * 8;
    const int tid = threadIdx.x;
    for (int idx = tid; idx < 5000; idx += 256) {
        int ci = idx / 625, e = idx - ci * 625;
        const float4* src = (const float4*)(x + ((size_t)(b * 64 + c0 + ci)) * TV + t0 * 25);
        float4 f = src[e];
        int p = e * 4;
        float vals[4] = { f.x, f.y, f.z, f.w };
        #pragma unroll
        for (int q = 0; q < 4; q++) {
            int pp = p + q;
            int tt = pp / 25, vv = pp - tt * 25;
            Ls[tt * 200 + ci * 25 + vv] = f2bf(vals[q]);
        }
    }
    __syncthreads();
    for (int i = tid; i < 2500; i += 256) {
        int tt = i / 25, w = i - tt * 25;
        uint4 d = *(uint4*)(Ls + tt * 200 + w * 8);
        *(uint4*)(X2 + ((size_t)(b * 300 + t0 + tt)) * GK + c0 * 25 + w * 8) = d;
    }
}

// ---------------- GEMM (m97 structure) with fused stats ----------------
// MODE 0: f32 out (pre-BN) + stats; MODE 1: bf16 Y[col][row] + stats; MODE 2: f32 out only
template<int MODE>
__global__ __launch_bounds__(256) void k_gemm(const unsigned short* __restrict__ X2,
                                              const unsigned short* __restrict__ Mt,
                                              float* __restrict__ outp,
                                              unsigned short* __restrict__ Y,
                                              float* __restrict__ psumc,
                                              float* __restrict__ psqc) {
    __shared__ __align__(16) unsigned short lds[2][8192];
    const int ctile = blockIdx.x, rtile = blockIdx.y;
    const int tid = threadIdx.x, wv = tid >> 6, ln = tid & 63;
    const int wr = wv >> 1, wc = wv & 1;

    const char* Ab = (const char*)X2 + (size_t)(rtile * 128 + (ln >> 2)) * 3200 + (ln & 3) * 16;
    const char* Bb = (const char*)Mt + (size_t)(ctile * 128 + (ln >> 2)) * 3200 + (ln & 3) * 16;

    f32x4 acc[4][4] = {};

    #define STAGE(buf, kt)                                                              \
    {                                                                                   \
        unsigned int kb = (unsigned int)(kt) * 64u;                                     \
        _Pragma("unroll")                                                               \
        for (int s = 0; s < 2; s++) {                                                   \
            int q = wv + s * 4;                                                         \
            __builtin_amdgcn_global_load_lds(                                           \
                (const __attribute__((address_space(1))) void*)(Ab + (size_t)q * 51200 + kb), \
                (__attribute__((address_space(3))) void*)(&lds[buf][0] + q * 512), 16, 0, 0); \
            __builtin_amdgcn_global_load_lds(                                           \
                (const __attribute__((address_space(1))) void*)(Bb + (size_t)q * 51200 + kb), \
                (__attribute__((address_space(3))) void*)(&lds[buf][4096] + q * 512), 16, 0, 0); \
        }                                                                               \
    }

    STAGE(0, 0)
    __syncthreads();
    int cur = 0;
    for (int kt = 0; kt < GK / 32; kt++) {
        if (kt < GK / 32 - 1) {
            if (cur == 0) STAGE(1, kt + 1) else STAGE(0, kt + 1)
        }
        const unsigned short* Al = &lds[cur][0];
        const unsigned short* Bl = &lds[cur][4096];
        bf16x8 af[4], bfv[4];
        #pragma unroll
        for (int i = 0; i < 4; i++) {
            af[i]  = *(const bf16x8*)(Al + (wr * 64 + i * 16 + (ln & 15)) * 32 + (ln >> 4) * 8);
            bfv[i] = *(const bf16x8*)(Bl + (wc * 64 + i * 16 + (ln & 15)) * 32 + (ln >> 4) * 8);
        }
        #pragma unroll
        for (int mi = 0; mi < 4; mi++)
            #pragma unroll
            for (int ni = 0; ni < 4; ni++)
                acc[mi][ni] = __builtin_amdgcn_mfma_f32_16x16x32_bf16(af[mi], bfv[ni], acc[mi][ni], 0, 0, 0);
        __syncthreads();
        cur ^= 1;
    }

    const int r0l = wr * 64 + (ln >> 4) * 4;   // local row base (tile row of first acc elem)
    const int c0l = wc * 64 + (ln & 15);       // local col base

    if (MODE == 1) {
        // bf16 Y[col][row]: 8B stores of 4 consecutive rows
        #pragma unroll
        for (int ni = 0; ni < 4; ni++) {
            const size_t colg = (size_t)(ctile * 128 + c0l + ni * 16);
            unsigned short* yb = Y + colg * 19200 + rtile * 128 + r0l;
            #pragma unroll
            for (int mi = 0; mi < 4; mi++) {
                uint2 d;
                d.x = pk2bf(acc[mi][ni][0], acc[mi][ni][1]);
                d.y = pk2bf(acc[mi][ni][2], acc[mi][ni][3]);
                *(uint2*)(yb + mi * 16) = d;
            }
        }
    } else {
        // f32 out[b,o,t,kv]
        const int r0 = rtile * 128 + r0l;
        const int n0 = ctile * 128 + c0l;
        #pragma unroll
        for (int ni = 0; ni < 4; ni++) {
            int col = n0 + ni * 16;
            int o = col / 25, kv = col - o * 25;
            #pragma unroll
            for (int mi = 0; mi < 4; mi++) {
                #pragma unroll
                for (int r = 0; r < 4; r++) {
                    int row = r0 + mi * 16 + r;
                    int b = row / 300, t = row - b * 300;
                    outp[(((size_t)(b * 128 + o)) * 300 + t) * 25 + kv] = acc[mi][ni][r];
                }
            }
        }
    }

    if (MODE == 0 || MODE == 1) {
        // fused BN partial stats: per-column sum & sumsq over this block's 128 rows
        float s[4], q[4];
        #pragma unroll
        for (int ni = 0; ni < 4; ni++) {
            float ss = 0.f, qq = 0.f;
            #pragma unroll
            for (int mi = 0; mi < 4; mi++)
                #pragma unroll
                for (int r = 0; r < 4; r++) {
                    float v = acc[mi][ni][r];
                    ss += v; qq += v * v;
                }
            ss += __shfl_xor(ss, 16); ss += __shfl_xor(ss, 32);
            qq += __shfl_xor(qq, 16); qq += __shfl_xor(qq, 32);
            s[ni] = ss; q[ni] = qq;
        }
        float* sbuf = (float*)(&lds[0][0]);   // reuse dead LDS (512 floats)
        float* qbuf = sbuf + 512;
        if (ln < 16) {
            #pragma unroll
            for (int ni = 0; ni < 4; ni++) {
                int cc = wc * 64 + ni * 16 + ln;
                sbuf[wv * 128 + cc] = s[ni];
                qbuf[wv * 128 + cc] = q[ni];
            }
        }
        __syncthreads();
        if (tid < 128) {
            int wcq = tid >> 6;
            float S = sbuf[wcq * 128 + tid] + sbuf[(wcq + 2) * 128 + tid];
            float Q = qbuf[wcq * 128 + tid] + qbuf[(wcq + 2) * 128 + tid];
            size_t idx = (size_t)(ctile * 128 + tid) * 150 + rtile;
            psumc[idx] = S;
            psqc[idx] = Q;
        }
    }
    #undef STAGE
}

// ---------------- finalize from per-(col,rtile) partials ----------------
__global__ __launch_bounds__(256) void k_finalize2(const float* __restrict__ psumc,
                                                   const float* __restrict__ psqc,
                                                   const float* __restrict__ gamma,
                                                   const float* __restrict__ beta,
                                                   float* __restrict__ scale,
                                                   float* __restrict__ shift) {
    const int o = blockIdx.x;
    const int tid = threadIdx.x;
    float S = 0.f, Q = 0.f;
    for (int i = tid; i < 3750; i += 256) {
        S += psumc[(size_t)o * 3750 + i];
        Q += psqc[(size_t)o * 3750 + i];
    }
    #pragma unroll
    for (int m = 1; m < 64; m <<= 1) { S += __shfl_xor(S, m); Q += __shfl_xor(Q, m); }
    __shared__ float ls[4], lq[4];
    int w = tid >> 6;
    if ((tid & 63) == 0) { ls[w] = S; lq[w] = Q; }
    __syncthreads();
    if (tid == 0) {
        float St = ls[0] + ls[1] + ls[2] + ls[3];
        float Qt = lq[0] + lq[1] + lq[2] + lq[3];
        float inv = 1.f / (float)BTV;
        float mean = St * inv;
        float var = Qt * inv - mean * mean;
        float sc = gamma[o] / sqrtf(var + 1e-5f);
        scale[o] = sc;
        shift[o] = beta[o] - mean * sc;
    }
}

// ---------------- norm from Y (bf16) -> out (f32), relayout ----------------
__global__ __launch_bounds__(256) void k_norm1(const unsigned short* __restrict__ Y,
                                               const float* __restrict__ scale,
                                               const float* __restrict__ shift,
                                               float* __restrict__ out) {
    __shared__ float tile[25][304];
    const int bo = blockIdx.x;           // b*128+o
    const int b = bo >> 7, o = bo & 127;
    const int tid = threadIdx.x;
    const float sc = scale[o], sh = shift[o];
    // stage: Y[(o*25+kv)][b*300 + t], coalesced u32 (2 rows)
    for (int i = tid; i < 3750; i += 256) {
        int kv = i / 150, tt = (i - kv * 150) * 2;
        unsigned int v = *(const unsigned int*)(Y + ((size_t)(o * 25 + kv)) * 19200 + b * 300 + tt);
        tile[kv][tt]     = bf2f((unsigned short)(v & 0xffffu));
        tile[kv][tt + 1] = bf2f((unsigned short)(v >> 16));
    }
    __syncthreads();
    // write: out[b,o,t,kv] as float4, fully coalesced
    float4* op = (float4*)(out + (size_t)bo * 7500);
    for (int i4 = tid; i4 < 1875; i4 += 256) {
        float4 d;
        float* dp = (float*)&d;
        #pragma unroll
        for (int e = 0; e < 4; e++) {
            int idx = i4 * 4 + e;
            int t = idx / 25, kv = idx - t * 25;
            dp[e] = fmaxf(fmaf(tile[kv][t], sc, sh), 0.f);
        }
        op[i4] = d;
    }
}

// ---------------- legacy BN kernels (MID / fallback paths) ----------------
__global__ __launch_bounds__(256) void k_stats(const float* __restrict__ out,
                                               float* __restrict__ psum,
                                               float* __restrict__ psq) {
    const int bo = blockIdx.x;
    const int b = bo >> 7, o = bo & 127;
    const float4* p = (const float4*)(out + (size_t)bo * TV);
    float s = 0.f, q = 0.f;
    for (int i = threadIdx.x; i < TV / 4; i += 256) {
        float4 v = p[i];
        s += v.x + v.y + v.z + v.w;
        q += v.x * v.x + v.y * v.y + v.z * v.z + v.w * v.w;
    }
    #pragma unroll
    for (int m = 1; m < 64; m <<= 1) { s += __shfl_xor(s, m); q += __shfl_xor(q, m); }
    __shared__ float ls[4], lq[4];
    int w = threadIdx.x >> 6;
    if ((threadIdx.x & 63) == 0) { ls[w] = s; lq[w] = q; }
    __syncthreads();
    if (threadIdx.x == 0) {
        psum[o * 64 + b] = ls[0] + ls[1] + ls[2] + ls[3];
        psq[o * 64 + b]  = lq[0] + lq[1] + lq[2] + lq[3];
    }
}

__global__ void k_finalize(const float* __restrict__ psum, const float* __restrict__ psq,
                           const float* __restrict__ gamma, const float* __restrict__ beta,
                           float* __restrict__ scale, float* __restrict__ shift) {
    int o = threadIdx.x;
    if (o >= 128) return;
    float S = 0.f, Q = 0.f;
    for (int j = 0; j < 64; j++) { S += psum[o * 64 + j]; Q += psq[o * 64 + j]; }
    float inv = 1.f / (float)BTV;
    float mean = S * inv;
    float var = Q * inv - mean * mean;
    float sc = gamma[o] / sqrtf(var + 1e-5f);
    scale[o] = sc;
    shift[o] = beta[o] - mean * sc;
}

__global__ __launch_bounds__(256) void k_norm0(float* __restrict__ out,
                                               const float* __restrict__ scale,
                                               const float* __restrict__ shift) {
    unsigned int f = blockIdx.x * 256u + threadIdx.x;
    int o = (int)((f / 1875u) & 127u);
    float sc = scale[o], sh = shift[o];
    float4* p = (float4*)out;
    float4 v = p[f];
    v.x = fmaxf(fmaf(v.x, sc, sh), 0.f);
    v.y = fmaxf(fmaf(v.y, sc, sh), 0.f);
    v.z = fmaxf(fmaf(v.z, sc, sh), 0.f);
    v.w = fmaxf(fmaf(v.w, sc, sh), 0.f);
    p[f] = v;
}

extern "C" void kernel_launch(void* const* d_in, const int* in_sizes, int n_in,
                              void* d_out, int out_size, void* d_ws, size_t ws_size,
                              hipStream_t stream) {
    const float* x     = (const float*)d_in[0];
    const float* A     = (const float*)d_in[1];
    const float* W     = (const float*)d_in[2];
    const float* Wr    = (const float*)d_in[3];
    const float* gamma = (const float*)d_in[5];
    const float* beta  = (const float*)d_in[6];
    float* out = (float*)d_out;
    char* wsb  = (char*)d_ws;

    unsigned short* X2 = (unsigned short*)(wsb + WSB_X2);
    unsigned short* Mt = (unsigned short*)(wsb + WSB_MT);
    float* apow = (float*)(wsb + WSB_APW);

    k_apow<<<1, 256, 0, stream>>>(A, apow);
    k_xpose<<<dim3(8, 3, 64), 256, 0, stream>>>(x, X2);
    k_prep<<<GN, 256, 0, stream>>>(W, Wr, apow, Mt);

    if (ws_size >= WS_NEED_FULL) {
        unsigned short* Y = (unsigned short*)(wsb + WSB_Y);
        float* psc = (float*)(wsb + WSB_PSC);
        float* psq = (float*)(wsb + WSB_PSQ);
        float* scl = (float*)(wsb + WSB_SCL);
        float* sft = (float*)(wsb + WSB_SFT);
        k_gemm<1><<<dim3(GN / 128, GM / 128), 256, 0, stream>>>(X2, Mt, out, Y, psc, psq);
        k_finalize2<<<128, 256, 0, stream>>>(psc, psq, gamma, beta, scl, sft);
        k_norm1<<<B_ * O_, 256, 0, stream>>>(Y, scl, sft, out);
    } else if (ws_size >= WS_NEED_MID) {
        float* psc = (float*)(wsb + WSM_PSC);
        float* psq = (float*)(wsb + WSM_PSQ);
        float* scl = (float*)(wsb + WSM_SCL);
        float* sft = (float*)(wsb + WSM_SFT);
        k_gemm<0><<<dim3(GN / 128, GM / 128), 256, 0, stream>>>(X2, Mt, out, (unsigned short*)nullptr, psc, psq);
        k_finalize2<<<128, 256, 0, stream>>>(psc, psq, gamma, beta, scl, sft);
        k_norm0<<<(out_size / 4) / 256, 256, 0, stream>>>(out, scl, sft);
    } else {
        // round-2 exact fallback (ws >= 71.77MB proven)
        float* ws = (float*)d_ws;
        float* psum  = ws + WS_PSUM;
        float* psq   = ws + WS_PSQ2;
        float* scale = ws + WS_SCALE;
        float* shift = ws + WS_SHIFT;
        k_gemm<2><<<dim3(GN / 128, GM / 128), 256, 0, stream>>>(X2, Mt, out, (unsigned short*)nullptr, (float*)nullptr, (float*)nullptr);
        k_stats<<<B_ * O_, 256, 0, stream>>>(out, psum, psq);
        k_finalize<<<1, 128, 0, stream>>>(psum, psq, gamma, beta, scale, shift);
        k_norm0<<<(out_size / 4) / 256, 256, 0, stream>>>(out, scale, shift);
    }
}

// Round 4
// 448.381 us; speedup vs baseline: 3.7720x; 1.0740x over previous
//
#include <hip/hip_runtime.h>
#include <hip/hip_bf16.h>

// Problem constants
#define B_  64
#define C_  64
#define T_  300
#define V_  25
#define O_  128
#define NADJ 8
#define TV  (T_*V_)     // 7500
#define BTV (B_*T_*V_)  // 480000

// GEMM view: M=19200 rows (b,t), N=3200 cols (o,k), K=1600 (c,j)
#define GM 19200
#define GN 3200
#define GK 1600
#define NKT (GK/32)     // 50 K-steps

typedef __bf16 bf16x8 __attribute__((ext_vector_type(8)));
typedef float f32x4 __attribute__((ext_vector_type(4)));

// ---- FULL ws layout (byte offsets) ----
#define WSB_X2    0ull          // 19200*1600*2 = 61,440,000
#define WSB_MT    61440000ull   // 3200*1600*2  = 10,240,000
#define WSB_APW   71680000ull   // (unused, kept for layout stability)
#define WSB_Y     71700000ull   // 3200*19200*2 = 122,880,000
#define WSB_PSC   194580000ull  // 3200*150*4 = 1,920,000
#define WSB_PSQ   196500000ull
#define WSB_SCL   198420000ull
#define WSB_SFT   198420512ull
#define WS_NEED_FULL 198421024ull

// ---- MID ws layout (no Y) ----
#define WSM_PSC   71700000ull
#define WSM_PSQ   73620000ull
#define WSM_SCL   75540000ull
#define WSM_SFT   75540512ull

static __device__ __forceinline__ unsigned short f2bf(float f) {
    unsigned int u = __float_as_uint(f);
    unsigned int r = (u + 0x7fffu + ((u >> 16) & 1u)) >> 16;
    return (unsigned short)r;
}
static __device__ __forceinline__ unsigned int pk2bf(float a, float b) {
    return (unsigned int)f2bf(a) | ((unsigned int)f2bf(b) << 16);
}
static __device__ __forceinline__ float bf2f(unsigned short u) {
    return __uint_as_float(((unsigned int)u) << 16);
}

// Mt[n][kk] bf16 = W[o,c]*A^{i+1}[j,kv] + Wr[o,c]*(j==kv), n=o*25+kv, kk=c*25+j
// A-power computed per-block by column power-iteration (A^{p+1}[:,kv] = A * A^p[:,kv]).
// Storage XOR-swizzled: 16B chunk cc stored at (cc&~3)|((cc&3)^(n&3)).
__global__ __launch_bounds__(256) void k_prep(const float* __restrict__ A,
                                              const float* __restrict__ W,
                                              const float* __restrict__ Wr,
                                              unsigned short* __restrict__ Mt) {
    const int n = blockIdx.x;
    const int o = n / 25, kv = n - o * 25;
    const int pw = o >> 4;               // extra multiplies: A^(pw+1)
    __shared__ float va[32], vb[32];
    const int tid = threadIdx.x;
    if (tid < 25) va[tid] = A[tid * 25 + kv];
    __syncthreads();
    float* cura = va; float* curb = vb;
    for (int s = 0; s < pw; s++) {
        if (tid < 25) {
            float acc = 0.f;
            #pragma unroll 5
            for (int m = 0; m < 25; m++) acc = fmaf(A[tid * 25 + m], cura[m], acc);
            curb[tid] = acc;
        }
        __syncthreads();
        float* tsw = cura; cura = curb; curb = tsw;
    }
    if (tid >= 200) return;
    const float* Wo  = W  + o * 64;
    const float* Wro = Wr + o * 64;
    unsigned short v[8];
    #pragma unroll
    for (int e = 0; e < 8; e++) {
        int kk = tid * 8 + e;
        int c = kk / 25, j = kk - c * 25;
        float val = Wo[c] * cura[j];
        if (j == kv) val += Wro[c];
        v[e] = f2bf(val);
    }
    const int cs = (tid & ~3) | ((tid & 3) ^ (n & 3));
    *(uint4*)(Mt + (size_t)n * GK + cs * 8) = *(uint4*)v;
}

// x[b,c,t,v] f32 -> X2[(b*300+t)][(c*25+v)] bf16, chunk-XOR-swizzled by row&3
__global__ __launch_bounds__(256) void k_xpose(const float* __restrict__ x,
                                               unsigned short* __restrict__ X2) {
    __shared__ unsigned short Ls[100 * 200];
    const int b = blockIdx.z, t0 = blockIdx.y * 100, c0 = blockIdx.x * 8;
    const int tid = threadIdx.x;
    for (int idx = tid; idx < 5000; idx += 256) {
        int ci = idx / 625, e = idx - ci * 625;
        const float4* src = (const float4*)(x + ((size_t)(b * 64 + c0 + ci)) * TV + t0 * 25);
        float4 f = src[e];
        int p = e * 4;
        float vals[4] = { f.x, f.y, f.z, f.w };
        #pragma unroll
        for (int q = 0; q < 4; q++) {
            int pp = p + q;
            int tt = pp / 25, vv = pp - tt * 25;
            Ls[tt * 200 + ci * 25 + vv] = f2bf(vals[q]);
        }
    }
    __syncthreads();
    const int ccbase = (c0 >> 3) * 25;
    for (int i = tid; i < 2500; i += 256) {
        int tt = i / 25, w = i - tt * 25;
        uint4 d = *(uint4*)(Ls + tt * 200 + w * 8);
        int row = b * 300 + t0 + tt;
        int cc = ccbase + w;
        int cs = (cc & ~3) | ((cc & 3) ^ (row & 3));
        *(uint4*)(X2 + (size_t)row * GK + cs * 8) = d;
    }
}

// ---------------- GEMM with fused BN stats ----------------
// MODE 0: f32 out + stats; MODE 1: bf16 Y[col][row] + stats
template<int MODE>
__global__ __launch_bounds__(256) void k_gemm(const unsigned short* __restrict__ X2,
                                              const unsigned short* __restrict__ Mt,
                                              float* __restrict__ outp,
                                              unsigned short* __restrict__ Y,
                                              float* __restrict__ psumc,
                                              float* __restrict__ psqc) {
    __shared__ __align__(16) unsigned short lds[2][8192];
    // ---- XCD-bijective (m204) + 5-ctile supertile remap; nwg=3750, q=468, r=6 ----
    const int lid = blockIdx.y * 25 + blockIdx.x;
    const int xcd = lid & 7, rest = lid >> 3;
    const int base = (xcd < 6) ? xcd * 469 : 2814 + (xcd - 6) * 468;
    const int wgid = base + rest;
    const int cgroup = wgid / 750;
    const int rem = wgid - cgroup * 750;
    const int rtile = rem / 5;
    const int ctile = cgroup * 5 + (rem - rtile * 5);

    const int tid = threadIdx.x, wv = tid >> 6, ln = tid & 63;
    const int wr = wv >> 1, wc = wv & 1;

    const char* Ab = (const char*)X2 + (size_t)(rtile * 128 + (ln >> 2)) * 3200 + (ln & 3) * 16;
    const char* Bb = (const char*)Mt + (size_t)(ctile * 128 + (ln >> 2)) * 3200 + (ln & 3) * 16;

    f32x4 acc[4][4] = {};

    #define STAGE(buf, kt)                                                              \
    {                                                                                   \
        unsigned int kb = (unsigned int)(kt) * 64u;                                     \
        _Pragma("unroll")                                                               \
        for (int s = 0; s < 2; s++) {                                                   \
            int q = wv + s * 4;                                                         \
            __builtin_amdgcn_global_load_lds(                                           \
                (const __attribute__((address_space(1))) void*)(Ab + (size_t)q * 51200 + kb), \
                (__attribute__((address_space(3))) void*)(&lds[buf][0] + q * 512), 16, 0, 0); \
            __builtin_amdgcn_global_load_lds(                                           \
                (const __attribute__((address_space(1))) void*)(Bb + (size_t)q * 51200 + kb), \
                (__attribute__((address_space(3))) void*)(&lds[buf][4096] + q * 512), 16, 0, 0); \
        }                                                                               \
    }

    // lane-constant swizzled chunk offset (shorts): logical chunk (ln>>4), row&3 == ln&3
    const int rdsw = ((ln >> 4) ^ (ln & 3)) * 8;
    const int arow = wr * 64 + (ln & 15);
    const int brow = wc * 64 + (ln & 15);

    #define COMPUTE(buf)                                                                \
    {                                                                                   \
        const unsigned short* Al = &lds[buf][0];                                        \
        const unsigned short* Bl = &lds[buf][4096];                                     \
        bf16x8 af[4], bfv[4];                                                           \
        _Pragma("unroll")                                                               \
        for (int i = 0; i < 4; i++) {                                                   \
            af[i]  = *(const bf16x8*)(Al + (arow + i * 16) * 32 + rdsw);                \
            bfv[i] = *(const bf16x8*)(Bl + (brow + i * 16) * 32 + rdsw);                \
        }                                                                               \
        _Pragma("unroll")                                                               \
        for (int mi = 0; mi < 4; mi++)                                                  \
            _Pragma("unroll")                                                           \
            for (int ni = 0; ni < 4; ni++)                                              \
                acc[mi][ni] = __builtin_amdgcn_mfma_f32_16x16x32_bf16(af[mi], bfv[ni], acc[mi][ni], 0, 0, 0); \
    }

    STAGE(0, 0)
    __syncthreads();
    int cur = 0;
    for (int kt = 0; kt < NKT - 1; kt++) {
        STAGE(cur ^ 1, kt + 1)
        COMPUTE(cur)
        __syncthreads();
        cur ^= 1;
    }
    COMPUTE(cur)

    const int r0l = wr * 64 + (ln >> 4) * 4;
    const int c0l = wc * 64 + (ln & 15);

    if (MODE == 1) {
        #pragma unroll
        for (int ni = 0; ni < 4; ni++) {
            const size_t colg = (size_t)(ctile * 128 + c0l + ni * 16);
            unsigned short* yb = Y + colg * 19200 + rtile * 128 + r0l;
            #pragma unroll
            for (int mi = 0; mi < 4; mi++) {
                uint2 d;
                d.x = pk2bf(acc[mi][ni][0], acc[mi][ni][1]);
                d.y = pk2bf(acc[mi][ni][2], acc[mi][ni][3]);
                *(uint2*)(yb + mi * 16) = d;
            }
        }
    } else {
        const int r0 = rtile * 128 + r0l;
        const int n0 = ctile * 128 + c0l;
        #pragma unroll
        for (int ni = 0; ni < 4; ni++) {
            int col = n0 + ni * 16;
            int o = col / 25, kv = col - o * 25;
            #pragma unroll
            for (int mi = 0; mi < 4; mi++) {
                #pragma unroll
                for (int r = 0; r < 4; r++) {
                    int row = r0 + mi * 16 + r;
                    int b = row / 300, t = row - b * 300;
                    outp[(((size_t)(b * 128 + o)) * 300 + t) * 25 + kv] = acc[mi][ni][r];
                }
            }
        }
    }

    // fused BN partials: per-column sum/sumsq of this block's 128 rows
    {
        float s[4], q[4];
        #pragma unroll
        for (int ni = 0; ni < 4; ni++) {
            float ss = 0.f, qq = 0.f;
            #pragma unroll
            for (int mi = 0; mi < 4; mi++)
                #pragma unroll
                for (int r = 0; r < 4; r++) {
                    float v = acc[mi][ni][r];
                    ss += v; qq += v * v;
                }
            ss += __shfl_xor(ss, 16); ss += __shfl_xor(ss, 32);
            qq += __shfl_xor(qq, 16); qq += __shfl_xor(qq, 32);
            s[ni] = ss; q[ni] = qq;
        }
        float* sbuf = (float*)(&lds[0][0]);
        float* qbuf = sbuf + 512;
        if (ln < 16) {
            #pragma unroll
            for (int ni = 0; ni < 4; ni++) {
                int cc = wc * 64 + ni * 16 + ln;
                sbuf[wv * 128 + cc] = s[ni];
                qbuf[wv * 128 + cc] = q[ni];
            }
        }
        __syncthreads();
        if (tid < 128) {
            int wcq = tid >> 6;
            float S = sbuf[wcq * 128 + tid] + sbuf[(wcq + 2) * 128 + tid];
            float Q = qbuf[wcq * 128 + tid] + qbuf[(wcq + 2) * 128 + tid];
            size_t idx = (size_t)(ctile * 128 + tid) * 150 + rtile;
            psumc[idx] = S;
            psqc[idx] = Q;
        }
    }
    #undef STAGE
    #undef COMPUTE
}

// ---------------- finalize from per-(col,rtile) partials ----------------
__global__ __launch_bounds__(256) void k_finalize2(const float* __restrict__ psumc,
                                                   const float* __restrict__ psqc,
                                                   const float* __restrict__ gamma,
                                                   const float* __restrict__ beta,
                                                   float* __restrict__ scale,
                                                   float* __restrict__ shift) {
    const int o = blockIdx.x;
    const int tid = threadIdx.x;
    float S = 0.f, Q = 0.f;
    for (int i = tid; i < 3750; i += 256) {
        S += psumc[(size_t)o * 3750 + i];
        Q += psqc[(size_t)o * 3750 + i];
    }
    #pragma unroll
    for (int m = 1; m < 64; m <<= 1) { S += __shfl_xor(S, m); Q += __shfl_xor(Q, m); }
    __shared__ float ls[4], lq[4];
    int w = tid >> 6;
    if ((tid & 63) == 0) { ls[w] = S; lq[w] = Q; }
    __syncthreads();
    if (tid == 0) {
        float St = ls[0] + ls[1] + ls[2] + ls[3];
        float Qt = lq[0] + lq[1] + lq[2] + lq[3];
        float inv = 1.f / (float)BTV;
        float mean = St * inv;
        float var = Qt * inv - mean * mean;
        float sc = gamma[o] / sqrtf(var + 1e-5f);
        scale[o] = sc;
        shift[o] = beta[o] - mean * sc;
    }
}

// ---------------- norm from Y (bf16) -> out (f32), relayout ----------------
__global__ __launch_bounds__(256) void k_norm1(const unsigned short* __restrict__ Y,
                                               const float* __restrict__ scale,
                                               const float* __restrict__ shift,
                                               float* __restrict__ out) {
    __shared__ float tile[25][304];
    const int bo = blockIdx.x;
    const int b = bo >> 7, o = bo & 127;
    const int tid = threadIdx.x;
    const float sc = scale[o], sh = shift[o];
    for (int i = tid; i < 3750; i += 256) {
        int kv = i / 150, tt = (i - kv * 150) * 2;
        unsigned int v = *(const unsigned int*)(Y + ((size_t)(o * 25 + kv)) * 19200 + b * 300 + tt);
        tile[kv][tt]     = bf2f((unsigned short)(v & 0xffffu));
        tile[kv][tt + 1] = bf2f((unsigned short)(v >> 16));
    }
    __syncthreads();
    float4* op = (float4*)(out + (size_t)bo * 7500);
    for (int i4 = tid; i4 < 1875; i4 += 256) {
        float4 d;
        float* dp = (float*)&d;
        #pragma unroll
        for (int e = 0; e < 4; e++) {
            int idx = i4 * 4 + e;
            int t = idx / 25, kv = idx - t * 25;
            dp[e] = fmaxf(fmaf(tile[kv][t], sc, sh), 0.f);
        }
        op[i4] = d;
    }
}

// ---------------- MID-path norm (in-place f32) ----------------
__global__ __launch_bounds__(256) void k_norm0(float* __restrict__ out,
                                               const float* __restrict__ scale,
                                               const float* __restrict__ shift) {
    unsigned int f = blockIdx.x * 256u + threadIdx.x;
    int o = (int)((f / 1875u) & 127u);
    float sc = scale[o], sh = shift[o];
    float4* p = (float4*)out;
    float4 v = p[f];
    v.x = fmaxf(fmaf(v.x, sc, sh), 0.f);
    v.y = fmaxf(fmaf(v.y, sc, sh), 0.f);
    v.z = fmaxf(fmaf(v.z, sc, sh), 0.f);
    v.w = fmaxf(fmaf(v.w, sc, sh), 0.f);
    p[f] = v;
}

extern "C" void kernel_launch(void* const* d_in, const int* in_sizes, int n_in,
                              void* d_out, int out_size, void* d_ws, size_t ws_size,
                              hipStream_t stream) {
    const float* x     = (const float*)d_in[0];
    const float* A     = (const float*)d_in[1];
    const float* W     = (const float*)d_in[2];
    const float* Wr    = (const float*)d_in[3];
    const float* gamma = (const float*)d_in[5];
    const float* beta  = (const float*)d_in[6];
    float* out = (float*)d_out;
    char* wsb  = (char*)d_ws;

    unsigned short* X2 = (unsigned short*)(wsb + WSB_X2);
    unsigned short* Mt = (unsigned short*)(wsb + WSB_MT);

    k_xpose<<<dim3(8, 3, 64), 256, 0, stream>>>(x, X2);
    k_prep<<<GN, 256, 0, stream>>>(A, W, Wr, Mt);

    if (ws_size >= WS_NEED_FULL) {
        unsigned short* Y = (unsigned short*)(wsb + WSB_Y);
        float* psc = (float*)(wsb + WSB_PSC);
        float* psq = (float*)(wsb + WSB_PSQ);
        float* scl = (float*)(wsb + WSB_SCL);
        float* sft = (float*)(wsb + WSB_SFT);
        k_gemm<1><<<dim3(GN / 128, GM / 128), 256, 0, stream>>>(X2, Mt, out, Y, psc, psq);
        k_finalize2<<<128, 256, 0, stream>>>(psc, psq, gamma, beta, scl, sft);
        k_norm1<<<B_ * O_, 256, 0, stream>>>(Y, scl, sft, out);
    } else {
        float* psc = (float*)(wsb + WSM_PSC);
        float* psq = (float*)(wsb + WSM_PSQ);
        float* scl = (float*)(wsb + WSM_SCL);
        float* sft = (float*)(wsb + WSM_SFT);
        k_gemm<0><<<dim3(GN / 128, GM / 128), 256, 0, stream>>>(X2, Mt, out, (unsigned short*)nullptr, psc, psq);
        k_finalize2<<<128, 256, 0, stream>>>(psc, psq, gamma, beta, scl, sft);
        k_norm0<<<(out_size / 4) / 256, 256, 0, stream>>>(out, scl, sft);
    }
}

// Round 5
// 396.184 us; speedup vs baseline: 4.2689x; 1.1317x over previous
//
#include <hip/hip_runtime.h>
#include <hip/hip_bf16.h>

// Problem constants
#define B_  64
#define C_  64
#define T_  300
#define V_  25
#define O_  128
#define TV  (T_*V_)     // 7500
#define BTV (B_*T_*V_)  // 480000

// GEMM view: M=19200 rows (b,t), N=3200 cols (o,k), K=1600 (c,j)
#define GM 19200
#define GN 3200
#define GK 1600
#define BM 256
#define BN 128
#define BK 64
#define NKT2 (GK/BK)    // 25 K-tiles
#define RT (GM/BM)      // 75
#define CT (GN/BN)      // 25
#define NWG (RT*CT)     // 1875

typedef __bf16 bf16x8 __attribute__((ext_vector_type(8)));
typedef float f32x4 __attribute__((ext_vector_type(4)));

// ---- FULL ws layout (byte offsets) ----
#define WSB_X2    0ull          // 19200*1600*2 = 61,440,000
#define WSB_MT    61440000ull   // 3200*1600*2  = 10,240,000
#define WSB_Y     71700000ull   // 3200*19200*2 = 122,880,000
#define WSB_PSC   194580000ull  // 3200*75*4 = 960,000 (slot 1.92MB)
#define WSB_PSQ   196500000ull
#define WSB_SCL   198420000ull
#define WSB_SFT   198420512ull
#define WS_NEED_FULL 198421024ull

// ---- MID ws layout (no Y) ----
#define WSM_PSC   71700000ull
#define WSM_PSQ   73620000ull
#define WSM_SCL   75540000ull
#define WSM_SFT   75540512ull

static __device__ __forceinline__ unsigned short f2bf(float f) {
    unsigned int u = __float_as_uint(f);
    unsigned int r = (u + 0x7fffu + ((u >> 16) & 1u)) >> 16;
    return (unsigned short)r;
}
static __device__ __forceinline__ unsigned int pk2bf(float a, float b) {
    return (unsigned int)f2bf(a) | ((unsigned int)f2bf(b) << 16);
}
static __device__ __forceinline__ float bf2f(unsigned short u) {
    return __uint_as_float(((unsigned int)u) << 16);
}

// Mt[n][kk] bf16 = W[o,c]*A^{i+1}[j,kv] + Wr[o,c]*(j==kv), n=o*25+kv, kk=c*25+j
// 16B chunk cc (0..199) stored at (cc&~7)|((cc&7)^(n&7))  [8-chunk XOR swizzle]
__global__ __launch_bounds__(256) void k_prep(const float* __restrict__ A,
                                              const float* __restrict__ W,
                                              const float* __restrict__ Wr,
                                              unsigned short* __restrict__ Mt) {
    const int n = blockIdx.x;
    const int o = n / 25, kv = n - o * 25;
    const int pw = o >> 4;
    __shared__ float va[32], vb[32];
    const int tid = threadIdx.x;
    if (tid < 25) va[tid] = A[tid * 25 + kv];
    __syncthreads();
    float* cura = va; float* curb = vb;
    for (int s = 0; s < pw; s++) {
        if (tid < 25) {
            float acc = 0.f;
            #pragma unroll 5
            for (int m = 0; m < 25; m++) acc = fmaf(A[tid * 25 + m], cura[m], acc);
            curb[tid] = acc;
        }
        __syncthreads();
        float* tsw = cura; cura = curb; curb = tsw;
    }
    if (tid >= 200) return;
    const float* Wo  = W  + o * 64;
    const float* Wro = Wr + o * 64;
    unsigned short v[8];
    #pragma unroll
    for (int e = 0; e < 8; e++) {
        int kk = tid * 8 + e;
        int c = kk / 25, j = kk - c * 25;
        float val = Wo[c] * cura[j];
        if (j == kv) val += Wro[c];
        v[e] = f2bf(val);
    }
    const int cs = (tid & ~7) | ((tid & 7) ^ (n & 7));
    *(uint4*)(Mt + (size_t)n * GK + cs * 8) = *(uint4*)v;
}

// x[b,c,t,v] f32 -> X2[(b*300+t)][(c*25+v)] bf16, 8-chunk XOR-swizzled by row&7
__global__ __launch_bounds__(256) void k_xpose(const float* __restrict__ x,
                                               unsigned short* __restrict__ X2) {
    __shared__ unsigned short Ls[100 * 200];
    const int b = blockIdx.z, t0 = blockIdx.y * 100, c0 = blockIdx.x * 8;
    const int tid = threadIdx.x;
    for (int idx = tid; idx < 5000; idx += 256) {
        int ci = idx / 625, e = idx - ci * 625;
        const float4* src = (const float4*)(x + ((size_t)(b * 64 + c0 + ci)) * TV + t0 * 25);
        float4 f = src[e];
        int p = e * 4;
        float vals[4] = { f.x, f.y, f.z, f.w };
        #pragma unroll
        for (int q = 0; q < 4; q++) {
            int pp = p + q;
            int tt = pp / 25, vv = pp - tt * 25;
            Ls[tt * 200 + ci * 25 + vv] = f2bf(vals[q]);
        }
    }
    __syncthreads();
    const int ccbase = (c0 >> 3) * 25;
    for (int i = tid; i < 2500; i += 256) {
        int tt = i / 25, w = i - tt * 25;
        uint4 d = *(uint4*)(Ls + tt * 200 + w * 8);
        int row = b * 300 + t0 + tt;
        int cc = ccbase + w;
        int cs = (cc & ~7) | ((cc & 7) ^ (row & 7));
        *(uint4*)(X2 + (size_t)row * GK + cs * 8) = d;
    }
}

// ---------------- GEMM: 256x128 tile, BK=64, 8 waves, triple-buffered LDS,
//                  counted-vmcnt multi-phase schedule, fused BN stats --------
// MODE 0: f32 out + stats; MODE 1: bf16 Y[col][row] + stats
template<int MODE>
__global__ __launch_bounds__(512) void k_gemm2(const unsigned short* __restrict__ X2,
                                               const unsigned short* __restrict__ Mt,
                                               float* __restrict__ outp,
                                               unsigned short* __restrict__ Y,
                                               float* __restrict__ psumc,
                                               float* __restrict__ psqc) {
    // per-buffer: A 256x64 shorts (32KB) + B 128x64 shorts (16KB) = 24576 shorts
    __shared__ __align__(16) unsigned short lds3[3 * 24576];   // 144 KB

    // XCD-bijective remap (nwg=1875, q=234, r=3) + 5-ctile supertile
    const int lid = blockIdx.x;
    const int xcd = lid & 7, rest = lid >> 3;
    const int base = (xcd < 3) ? xcd * 235 : 705 + (xcd - 3) * 234;
    const int wgid = base + rest;
    const int cgroup = wgid / 375;
    const int rem = wgid - cgroup * 375;
    const int rtile = rem / 5;
    const int ctile = cgroup * 5 + (rem - rtile * 5);

    const int tid = threadIdx.x, wv = tid >> 6, ln = tid & 63;
    const int wr = wv >> 1, wc = wv & 1;

    // staging source bases: lane l handles row (l>>3), memory chunk (l&7)
    const char* Abg = (const char*)X2 + (size_t)(rtile * 256 + (ln >> 3)) * 3200 + (ln & 7) * 16;
    const char* Bbg = (const char*)Mt + (size_t)(ctile * 128 + (ln >> 3)) * 3200 + (ln & 7) * 16;

    f32x4 acc[4][4] = {};

    // half h of K-tile kt into buffer bufp: 2 A-loads + 1 B-load (per wave)
    #define STAGEHALF(bufp, kt, h)                                                       \
    {                                                                                    \
        unsigned int kb = (unsigned int)(kt) * 128u;                                     \
        _Pragma("unroll")                                                                \
        for (int s = 0; s < 2; s++) {                                                    \
            int rr = wv * 32 + (h) * 16 + s * 8;                                         \
            __builtin_amdgcn_global_load_lds(                                            \
                (const __attribute__((address_space(1))) void*)(Abg + (size_t)rr * 3200 + kb), \
                (__attribute__((address_space(3))) void*)(lds3 + (bufp) * 24576 + rr * 64), 16, 0, 0); \
        }                                                                                \
        {                                                                                \
            int rb = wv * 16 + (h) * 8;                                                  \
            __builtin_amdgcn_global_load_lds(                                            \
                (const __attribute__((address_space(1))) void*)(Bbg + (size_t)rb * 3200 + kb), \
                (__attribute__((address_space(3))) void*)(lds3 + (bufp) * 24576 + 16384 + rb * 64), 16, 0, 0); \
        }                                                                                \
    }

    // fragment read offsets (shorts); row&7 == ln&7 (stripe bases are %8==0)
    const int arow0 = (wr * 64 + (ln & 15)) * 64;
    const int brow0 = (wc * 64 + (ln & 15)) * 64;
    const int sw0 = ((ln >> 4) ^ (ln & 7)) * 8;   // ks=0 chunk; ks=1 is sw0^32

    #define PHASE(bufp, swk)                                                             \
    {                                                                                    \
        const unsigned short* As = lds3 + (bufp) * 24576;                                \
        const unsigned short* Bs = As + 16384;                                           \
        bf16x8 af[4], bv[4];                                                             \
        _Pragma("unroll")                                                                \
        for (int mi = 0; mi < 4; mi++) af[mi] = *(const bf16x8*)(As + arow0 + mi * 1024 + (swk)); \
        _Pragma("unroll")                                                                \
        for (int ni = 0; ni < 4; ni++) bv[ni] = *(const bf16x8*)(Bs + brow0 + ni * 1024 + (swk)); \
        __builtin_amdgcn_s_setprio(1);                                                   \
        _Pragma("unroll")                                                                \
        for (int mi = 0; mi < 4; mi++)                                                   \
            _Pragma("unroll")                                                            \
            for (int ni = 0; ni < 4; ni++)                                               \
                acc[mi][ni] = __builtin_amdgcn_mfma_f32_16x16x32_bf16(af[mi], bv[ni], acc[mi][ni], 0, 0, 0); \
        __builtin_amdgcn_s_setprio(0);                                                   \
    }

    // prologue: stage kt=0 -> buf0, kt=1 -> buf1
    STAGEHALF(0, 0, 0) STAGEHALF(0, 0, 1)
    STAGEHALF(1, 1, 0) STAGEHALF(1, 1, 1)

    int bc = 0;   // buffer holding kt
    #pragma unroll 1
    for (int kt = 0; kt < NKT2 - 1; kt++) {
        asm volatile("s_waitcnt vmcnt(6)" ::: "memory");
        __builtin_amdgcn_s_barrier();
        asm volatile("" ::: "memory");
        __builtin_amdgcn_sched_barrier(0);
        int bs = bc + 2; if (bs >= 3) bs -= 3;
        if (kt < NKT2 - 2) STAGEHALF(bs, kt + 2, 0)
        PHASE(bc, sw0)
        if (kt < NKT2 - 2) STAGEHALF(bs, kt + 2, 1)
        PHASE(bc, sw0 ^ 32)
        bc = (bc + 1 == 3) ? 0 : bc + 1;
    }
    // last K-tile
    asm volatile("s_waitcnt vmcnt(0)" ::: "memory");
    __builtin_amdgcn_s_barrier();
    asm volatile("" ::: "memory");
    __builtin_amdgcn_sched_barrier(0);
    PHASE(bc, sw0)
    PHASE(bc, sw0 ^ 32)

    // ---- epilogue ----
    const int r0l = wr * 64 + (ln >> 4) * 4;
    const int c0l = wc * 64 + (ln & 15);

    if (MODE == 1) {
        #pragma unroll
        for (int ni = 0; ni < 4; ni++) {
            const size_t colg = (size_t)(ctile * 128 + c0l + ni * 16);
            unsigned short* yb = Y + colg * 19200 + rtile * 256 + r0l;
            #pragma unroll
            for (int mi = 0; mi < 4; mi++) {
                uint2 d;
                d.x = pk2bf(acc[mi][ni][0], acc[mi][ni][1]);
                d.y = pk2bf(acc[mi][ni][2], acc[mi][ni][3]);
                *(uint2*)(yb + mi * 16) = d;
            }
        }
    } else {
        const int r0 = rtile * 256 + r0l;
        const int n0 = ctile * 128 + c0l;
        #pragma unroll
        for (int ni = 0; ni < 4; ni++) {
            int col = n0 + ni * 16;
            int o = col / 25, kv = col - o * 25;
            #pragma unroll
            for (int mi = 0; mi < 4; mi++) {
                #pragma unroll
                for (int r = 0; r < 4; r++) {
                    int row = r0 + mi * 16 + r;
                    int b = row / 300, t = row - b * 300;
                    outp[(((size_t)(b * 128 + o)) * 300 + t) * 25 + kv] = acc[mi][ni][r];
                }
            }
        }
    }

    // fused BN partials: per-column sum/sumsq over this block's 256 rows
    {
        float s[4], q[4];
        #pragma unroll
        for (int ni = 0; ni < 4; ni++) {
            float ss = 0.f, qq = 0.f;
            #pragma unroll
            for (int mi = 0; mi < 4; mi++)
                #pragma unroll
                for (int r = 0; r < 4; r++) {
                    float v = acc[mi][ni][r];
                    ss += v; qq += v * v;
                }
            ss += __shfl_xor(ss, 16); ss += __shfl_xor(ss, 32);
            qq += __shfl_xor(qq, 16); qq += __shfl_xor(qq, 32);
            s[ni] = ss; q[ni] = qq;
        }
        __syncthreads();                       // all reads of lds3 done; reuse for stats
        float* sbuf = (float*)lds3;            // [8 waves][64 cols]
        float* qbuf = sbuf + 512;
        if (ln < 16) {
            #pragma unroll
            for (int ni = 0; ni < 4; ni++) {
                sbuf[wv * 64 + ni * 16 + ln] = s[ni];
                qbuf[wv * 64 + ni * 16 + ln] = q[ni];
            }
        }
        __syncthreads();
        if (tid < 128) {
            int half = tid >> 6;               // which wc stripe
            int cl = tid & 63;
            float S = 0.f, Q = 0.f;
            #pragma unroll
            for (int wrp = 0; wrp < 4; wrp++) {
                int wvv = wrp * 2 + half;
                S += sbuf[wvv * 64 + cl];
                Q += qbuf[wvv * 64 + cl];
            }
            size_t idx = (size_t)(ctile * 128 + tid) * RT + rtile;
            psumc[idx] = S;
            psqc[idx] = Q;
        }
    }
    #undef STAGEHALF
    #undef PHASE
}

// ---------------- finalize from per-(col,rtile) partials ----------------
__global__ __launch_bounds__(256) void k_finalize2(const float* __restrict__ psumc,
                                                   const float* __restrict__ psqc,
                                                   const float* __restrict__ gamma,
                                                   const float* __restrict__ beta,
                                                   float* __restrict__ scale,
                                                   float* __restrict__ shift) {
    const int o = blockIdx.x;
    const int tid = threadIdx.x;
    float S = 0.f, Q = 0.f;
    for (int i = tid; i < 25 * RT; i += 256) {
        S += psumc[(size_t)o * 25 * RT + i];
        Q += psqc[(size_t)o * 25 * RT + i];
    }
    #pragma unroll
    for (int m = 1; m < 64; m <<= 1) { S += __shfl_xor(S, m); Q += __shfl_xor(Q, m); }
    __shared__ float ls[4], lq[4];
    int w = tid >> 6;
    if ((tid & 63) == 0) { ls[w] = S; lq[w] = Q; }
    __syncthreads();
    if (tid == 0) {
        float St = ls[0] + ls[1] + ls[2] + ls[3];
        float Qt = lq[0] + lq[1] + lq[2] + lq[3];
        float inv = 1.f / (float)BTV;
        float mean = St * inv;
        float var = Qt * inv - mean * mean;
        float sc = gamma[o] / sqrtf(var + 1e-5f);
        scale[o] = sc;
        shift[o] = beta[o] - mean * sc;
    }
}

// ---------------- norm from Y (bf16) -> out (f32), relayout ----------------
__global__ __launch_bounds__(256) void k_norm1(const unsigned short* __restrict__ Y,
                                               const float* __restrict__ scale,
                                               const float* __restrict__ shift,
                                               float* __restrict__ out) {
    __shared__ float tile[25][304];
    const int bo = blockIdx.x;
    const int b = bo >> 7, o = bo & 127;
    const int tid = threadIdx.x;
    const float sc = scale[o], sh = shift[o];
    for (int i = tid; i < 3750; i += 256) {
        int kv = i / 150, tt = (i - kv * 150) * 2;
        unsigned int v = *(const unsigned int*)(Y + ((size_t)(o * 25 + kv)) * 19200 + b * 300 + tt);
        tile[kv][tt]     = bf2f((unsigned short)(v & 0xffffu));
        tile[kv][tt + 1] = bf2f((unsigned short)(v >> 16));
    }
    __syncthreads();
    float4* op = (float4*)(out + (size_t)bo * 7500);
    for (int i4 = tid; i4 < 1875; i4 += 256) {
        float4 d;
        float* dp = (float*)&d;
        #pragma unroll
        for (int e = 0; e < 4; e++) {
            int idx = i4 * 4 + e;
            int t = idx / 25, kv = idx - t * 25;
            dp[e] = fmaxf(fmaf(tile[kv][t], sc, sh), 0.f);
        }
        op[i4] = d;
    }
}

// ---------------- MID-path norm (in-place f32) ----------------
__global__ __launch_bounds__(256) void k_norm0(float* __restrict__ out,
                                               const float* __restrict__ scale,
                                               const float* __restrict__ shift) {
    unsigned int f = blockIdx.x * 256u + threadIdx.x;
    int o = (int)((f / 1875u) & 127u);
    float sc = scale[o], sh = shift[o];
    float4* p = (float4*)out;
    float4 v = p[f];
    v.x = fmaxf(fmaf(v.x, sc, sh), 0.f);
    v.y = fmaxf(fmaf(v.y, sc, sh), 0.f);
    v.z = fmaxf(fmaf(v.z, sc, sh), 0.f);
    v.w = fmaxf(fmaf(v.w, sc, sh), 0.f);
    p[f] = v;
}

extern "C" void kernel_launch(void* const* d_in, const int* in_sizes, int n_in,
                              void* d_out, int out_size, void* d_ws, size_t ws_size,
                              hipStream_t stream) {
    const float* x     = (const float*)d_in[0];
    const float* A     = (const float*)d_in[1];
    const float* W     = (const float*)d_in[2];
    const float* Wr    = (const float*)d_in[3];
    const float* gamma = (const float*)d_in[5];
    const float* beta  = (const float*)d_in[6];
    float* out = (float*)d_out;
    char* wsb  = (char*)d_ws;

    unsigned short* X2 = (unsigned short*)(wsb + WSB_X2);
    unsigned short* Mt = (unsigned short*)(wsb + WSB_MT);

    k_xpose<<<dim3(8, 3, 64), 256, 0, stream>>>(x, X2);
    k_prep<<<GN, 256, 0, stream>>>(A, W, Wr, Mt);

    if (ws_size >= WS_NEED_FULL) {
        unsigned short* Y = (unsigned short*)(wsb + WSB_Y);
        float* psc = (float*)(wsb + WSB_PSC);
        float* psq = (float*)(wsb + WSB_PSQ);
        float* scl = (float*)(wsb + WSB_SCL);
        float* sft = (float*)(wsb + WSB_SFT);
        k_gemm2<1><<<NWG, 512, 0, stream>>>(X2, Mt, out, Y, psc, psq);
        k_finalize2<<<128, 256, 0, stream>>>(psc, psq, gamma, beta, scl, sft);
        k_norm1<<<B_ * O_, 256, 0, stream>>>(Y, scl, sft, out);
    } else {
        float* psc = (float*)(wsb + WSM_PSC);
        float* psq = (float*)(wsb + WSM_PSQ);
        float* scl = (float*)(wsb + WSM_SCL);
        float* sft = (float*)(wsb + WSM_SFT);
        k_gemm2<0><<<NWG, 512, 0, stream>>>(X2, Mt, out, (unsigned short*)nullptr, psc, psq);
        k_finalize2<<<128, 256, 0, stream>>>(psc, psq, gamma, beta, scl, sft);
        k_norm0<<<(out_size / 4) / 256, 256, 0, stream>>>(out, scl, sft);
    }
}

// Round 6
// 308.397 us; speedup vs baseline: 5.4841x; 1.2847x over previous
//
#include <hip/hip_runtime.h>
#include <hip/hip_bf16.h>

// Problem constants
#define B_  64
#define C_  64
#define T_  300
#define V_  25
#define O_  128
#define TV  (T_*V_)     // 7500
#define BTV (B_*T_*V_)  // 480000
#define NROW 480000     // B*T*V rows of H
#define NP2  4800       // pass2 blocks (19200 slabs / 4)

typedef __bf16 bf16x8 __attribute__((ext_vector_type(8)));
typedef float f32x4 __attribute__((ext_vector_type(4)));

// ---- ws layout (byte offsets). Proven ws_size >= 198,421,024 in rounds 3-5. ----
#define WSB_APW   0ull           // padded A-powers: 8*25*28 f32 = 22400, slot 22528
#define WSB_WT    22528ull       // Wt[256][64] bf16 pre-swizzled = 32768
#define WSB_PSC   55296ull       // [128][4800] f32 = 2,457,600
#define WSB_PSQ   2512896ull     // same
#define WSB_SCL   4970496ull     // 128 f32 (slot 512)
#define WSB_SFT   4971008ull
#define WSB_Y     4971520ull     // [B*128][7500] bf16 = 122,880,000
#define WS_NEED2  127851520ull

static __device__ __forceinline__ unsigned short f2bf(float f) {
    unsigned int u = __float_as_uint(f);
    unsigned int r = (u + 0x7fffu + ((u >> 16) & 1u)) >> 16;
    return (unsigned short)r;
}
static __device__ __forceinline__ unsigned int pk2bf(float a, float b) {
    return (unsigned int)f2bf(a) | ((unsigned int)f2bf(b) << 16);
}
static __device__ __forceinline__ float bf2f(unsigned short u) {
    return __uint_as_float(((unsigned int)u) << 16);
}

#define GLL(SRC, DST) __builtin_amdgcn_global_load_lds( \
    (const __attribute__((address_space(1))) void*)(SRC), \
    (__attribute__((address_space(3))) void*)(DST), 16, 0, 0)

// ---------------- A powers, padded layout apw[(i*25+j)*28 + k] = A^{i+1}[j,k] ----
__global__ __launch_bounds__(256) void k_apow2(const float* __restrict__ A,
                                               float* __restrict__ apw) {
    __shared__ float P[2][625];
    const int tid = threadIdx.x;
    for (int p = tid; p < 625; p += 256) P[0][p] = A[p];
    for (int idx = tid; idx < 5632; idx += 256) apw[idx] = 0.f;  // zero incl. pads
    __syncthreads();
    int cur = 0;
    for (int i = 0; i < 8; i++) {
        if (i > 0) {
            for (int p = tid; p < 625; p += 256) {
                int r = p / 25, c2 = p - r * 25;
                float s = 0.f;
                #pragma unroll 5
                for (int j = 0; j < 25; j++) s = fmaf(P[cur][r*25 + j], A[j*25 + c2], s);
                P[cur ^ 1][p] = s;
            }
            __syncthreads();
            cur ^= 1;
        }
        for (int p = tid; p < 625; p += 256) {
            int r = p / 25, c2 = p - r * 25;
            apw[(i * 25 + r) * 28 + c2] = P[cur][p];
        }
        __syncthreads();
    }
}

// ---------------- Wt[oc][c] bf16, chunk-XOR swizzled (cc ^ (oc&7)) ----------------
// oc<128 -> W[oc][c]; oc>=128 -> Wr[oc-128][c]
__global__ __launch_bounds__(256) void k_wt(const float* __restrict__ W,
                                            const float* __restrict__ Wr,
                                            unsigned short* __restrict__ Wt) {
    const int oc = threadIdx.x;
    const float* src = (oc < 128) ? (W + oc * 64) : (Wr + (oc - 128) * 64);
    unsigned short row[64];
    #pragma unroll
    for (int c = 0; c < 64; c++) row[c] = f2bf(src[c]);
    #pragma unroll
    for (int cc = 0; cc < 8; cc++)
        *(uint4*)(Wt + oc * 64 + ((cc ^ (oc & 7)) << 3)) = *(uint4*)(row + cc * 8);
}

// ---------------- K=64 GEMM with fused x-transpose: HR[(b,t,v)][256] bf16 ----------
// grid (59, 64), 512 threads. HR stored in d_out (exact 245,760,000 B fit).
__global__ __launch_bounds__(512) void k_g1(const float* __restrict__ x,
                                            const unsigned short* __restrict__ Wt,
                                            unsigned short* __restrict__ HR) {
    __shared__ __align__(16) unsigned short As[128 * 64];   // 16 KB
    __shared__ __align__(16) unsigned short Bs[256 * 64];   // 32 KB
    const int q = blockIdx.x, b = blockIdx.y;
    const int tv0 = q * 128;
    const int rows_valid = (tv0 + 128 <= TV) ? 128 : (TV - tv0);   // 128 or 76
    const int tid = threadIdx.x, wv = tid >> 6, ln = tid & 63;

    // B stage: linear copy of pre-swizzled Wt (32 KB)
    #pragma unroll
    for (int i = 0; i < 4; i++) {
        int seg = i * 8 + wv;
        GLL((const char*)Wt + seg * 1024 + ln * 16, (char*)Bs + seg * 1024);
    }
    // A stage: x[b][c][tv0..] f32 -> bf16 into swizzled As[row=tv][c]
    {
        const int c = tid >> 3, grp = tid & 7;
        const float* xs = x + ((size_t)(b * 64 + c)) * TV + tv0 + grp * 16;
        if (grp * 16 + 16 <= rows_valid) {
            #pragma unroll
            for (int e4 = 0; e4 < 4; e4++) {
                float4 f = *(const float4*)(xs + e4 * 4);
                float vv[4] = { f.x, f.y, f.z, f.w };
                #pragma unroll
                for (int u = 0; u < 4; u++) {
                    int row = grp * 16 + e4 * 4 + u;
                    As[row * 64 + (((c >> 3) ^ (row & 7)) << 3) + (c & 7)] = f2bf(vv[u]);
                }
            }
        } else {
            for (int e = 0; e < 16; e++) {
                int row = grp * 16 + e;
                float f = (row < rows_valid) ? xs[e] : 0.f;
                As[row * 64 + (((c >> 3) ^ (row & 7)) << 3) + (c & 7)] = f2bf(f);
            }
        }
    }
    asm volatile("s_waitcnt vmcnt(0)" ::: "memory");
    __syncthreads();

    const int wr = wv >> 2, wc = wv & 3;    // 2M x 4N waves, 64x64 each (128x256 tile)
    f32x4 acc[4][4] = {};
    #pragma unroll
    for (int ks = 0; ks < 2; ks++) {
        const int ch = (((ks * 4 + (ln >> 4)) ^ (ln & 7)) << 3);
        bf16x8 af[4], bv[4];
        #pragma unroll
        for (int mi = 0; mi < 4; mi++)
            af[mi] = *(const bf16x8*)(As + (wr * 64 + mi * 16 + (ln & 15)) * 64 + ch);
        #pragma unroll
        for (int ni = 0; ni < 4; ni++)
            bv[ni] = *(const bf16x8*)(Bs + (wc * 64 + ni * 16 + (ln & 15)) * 64 + ch);
        // swapped operands: D[reg -> oc (4 consecutive)], [lane&15 -> tv-row]
        #pragma unroll
        for (int mi = 0; mi < 4; mi++)
            #pragma unroll
            for (int ni = 0; ni < 4; ni++)
                acc[mi][ni] = __builtin_amdgcn_mfma_f32_16x16x32_bf16(bv[ni], af[mi], acc[mi][ni], 0, 0, 0);
    }
    // epilogue: HR row = b*7500 + tv0 + m; cols wc*64 + ni*16 + (ln>>4)*4 + e
    #pragma unroll
    for (int mi = 0; mi < 4; mi++) {
        int mloc = wr * 64 + mi * 16 + (ln & 15);
        if (mloc < rows_valid) {
            unsigned short* hb = HR + ((size_t)(b * TV + tv0 + mloc)) * 256 + wc * 64 + (ln >> 4) * 4;
            #pragma unroll
            for (int ni = 0; ni < 4; ni++) {
                uint2 d;
                d.x = pk2bf(acc[mi][ni][0], acc[mi][ni][1]);
                d.y = pk2bf(acc[mi][ni][2], acc[mi][ni][3]);
                *(uint2*)(hb + ni * 16) = d;
            }
        }
    }
}

// ---------------- pass2: graph-apply + residual + BN partials + Y (final layout) ----
// block = 4 slabs (b, t0..t0+3); 256 threads = 4 waves (wave = slab), lane = o-pair.
__global__ __launch_bounds__(256) void k_pass2(const unsigned short* __restrict__ HR,
                                               const float* __restrict__ apw_g,
                                               unsigned short* __restrict__ Y,
                                               float* __restrict__ psc,
                                               float* __restrict__ psq) {
    __shared__ __align__(16) unsigned short Hs[100 * 256];  // 50 KB; Yt overlays later
    __shared__ __align__(16) float Apw[5632];               // 22 KB padded A-powers
    __shared__ float ssum[512], ssq[512];
    const int blk = blockIdx.x;
    const int b = blk / 75, tg = blk - b * 75, t0 = tg * 4;
    const int tid = threadIdx.x, wv = tid >> 6, ln = tid & 63;

    const char* hsrc = (const char*)(HR + ((size_t)b * TV + t0 * 25) * 256);
    #pragma unroll
    for (int i = 0; i < 13; i++) {
        int seg = wv + i * 4;
        if (seg < 50) GLL(hsrc + seg * 1024 + ln * 16, (char*)Hs + seg * 1024);
    }
    #pragma unroll
    for (int i = 0; i < 6; i++) {
        int seg = wv + i * 4;
        if (seg < 22) GLL((const char*)apw_g + seg * 1024 + ln * 16, (char*)Apw + seg * 1024);
    }
    asm volatile("s_waitcnt vmcnt(0)" ::: "memory");
    __syncthreads();

    const int s = wv;            // slab (t = t0+s)
    const int o0 = ln * 2;
    const float* Ai = Apw + (o0 >> 4) * 700;    // 700 = 25*28
    float acc0[25], acc1[25];
    #pragma unroll
    for (int k = 0; k < 25; k++) { acc0[k] = 0.f; acc1[k] = 0.f; }
    for (int j = 0; j < 25; j++) {
        unsigned int hh = *(const unsigned int*)(Hs + (s * 25 + j) * 256 + o0);
        float h0 = bf2f((unsigned short)(hh & 0xffffu));
        float h1 = bf2f((unsigned short)(hh >> 16));
        const float4* ar = (const float4*)(Ai + j * 28);
        #pragma unroll
        for (int qd = 0; qd < 6; qd++) {
            float4 a = ar[qd];
            acc0[qd*4+0] = fmaf(h0, a.x, acc0[qd*4+0]); acc1[qd*4+0] = fmaf(h1, a.x, acc1[qd*4+0]);
            acc0[qd*4+1] = fmaf(h0, a.y, acc0[qd*4+1]); acc1[qd*4+1] = fmaf(h1, a.y, acc1[qd*4+1]);
            acc0[qd*4+2] = fmaf(h0, a.z, acc0[qd*4+2]); acc1[qd*4+2] = fmaf(h1, a.z, acc1[qd*4+2]);
            acc0[qd*4+3] = fmaf(h0, a.w, acc0[qd*4+3]); acc1[qd*4+3] = fmaf(h1, a.w, acc1[qd*4+3]);
        }
        float a24 = Ai[j * 28 + 24];
        acc0[24] = fmaf(h0, a24, acc0[24]); acc1[24] = fmaf(h1, a24, acc1[24]);
    }
    // residual: + HR[(b,t,k)][128+o]
    #pragma unroll
    for (int k = 0; k < 25; k++) {
        unsigned int rr = *(const unsigned int*)(Hs + (s * 25 + k) * 256 + 128 + o0);
        acc0[k] += bf2f((unsigned short)(rr & 0xffffu));
        acc1[k] += bf2f((unsigned short)(rr >> 16));
    }
    // BN partials
    float s0 = 0.f, q0 = 0.f, s1 = 0.f, q1 = 0.f;
    #pragma unroll
    for (int k = 0; k < 25; k++) {
        s0 += acc0[k]; q0 += acc0[k] * acc0[k];
        s1 += acc1[k]; q1 += acc1[k] * acc1[k];
    }
    ssum[s * 128 + o0] = s0; ssum[s * 128 + o0 + 1] = s1;
    ssq [s * 128 + o0] = q0; ssq [s * 128 + o0 + 1] = q1;
    __syncthreads();                       // all Hs reads done; ssum visible
    // Yt overlay on Hs: [o][104] shorts, cols s*25+k
    unsigned short* Yt = Hs;
    #pragma unroll
    for (int k = 0; k < 25; k++) {
        Yt[o0 * 104 + s * 25 + k]       = f2bf(acc0[k]);
        Yt[(o0 + 1) * 104 + s * 25 + k] = f2bf(acc1[k]);
    }
    if (tid < 128) {
        float S = ssum[tid] + ssum[128 + tid] + ssum[256 + tid] + ssum[384 + tid];
        float Q = ssq[tid]  + ssq[128 + tid]  + ssq[256 + tid]  + ssq[384 + tid];
        psc[(size_t)tid * NP2 + blk] = S;
        psq[(size_t)tid * NP2 + blk] = Q;
    }
    __syncthreads();
    // Y[(b*128+o)][t0*25 .. +100) : 25 uint2 per o, 8B-aligned (t0 % 4 == 0)
    for (int idx = tid; idx < 3200; idx += 256) {
        int o = idx / 25, ch = idx - o * 25;
        uint2 d = *(const uint2*)(Yt + o * 104 + ch * 4);
        *(uint2*)(Y + ((size_t)(b * 128 + o)) * TV + t0 * 25 + ch * 4) = d;
    }
}

// ---------------- finalize BN from per-(o,blk) partials ----------------
__global__ __launch_bounds__(256) void k_finalize3(const float* __restrict__ psc,
                                                   const float* __restrict__ psq,
                                                   const float* __restrict__ gamma,
                                                   const float* __restrict__ beta,
                                                   float* __restrict__ scale,
                                                   float* __restrict__ shift) {
    const int o = blockIdx.x, tid = threadIdx.x;
    float S = 0.f, Q = 0.f;
    for (int i = tid; i < NP2; i += 256) {
        S += psc[(size_t)o * NP2 + i];
        Q += psq[(size_t)o * NP2 + i];
    }
    #pragma unroll
    for (int m = 1; m < 64; m <<= 1) { S += __shfl_xor(S, m); Q += __shfl_xor(Q, m); }
    __shared__ float ls[4], lq[4];
    int w = tid >> 6;
    if ((tid & 63) == 0) { ls[w] = S; lq[w] = Q; }
    __syncthreads();
    if (tid == 0) {
        float St = ls[0] + ls[1] + ls[2] + ls[3];
        float Qt = lq[0] + lq[1] + lq[2] + lq[3];
        float inv = 1.f / (float)BTV;
        float mean = St * inv;
        float var = Qt * inv - mean * mean;
        float sc = gamma[o] / sqrtf(var + 1e-5f);
        scale[o] = sc;
        shift[o] = beta[o] - mean * sc;
    }
}

// ---------------- norm: Y bf16 (final layout) -> out f32, fully linear ----------
__global__ __launch_bounds__(256) void k_norm2(const unsigned short* __restrict__ Y,
                                               const float* __restrict__ scale,
                                               const float* __restrict__ shift,
                                               float* __restrict__ out) {
    size_t e0 = ((size_t)blockIdx.x * 256 + threadIdx.x) * 8;
    #pragma unroll
    for (int g = 0; g < 2; g++) {
        size_t e = e0 + (size_t)g * 4;                 // 4-elem group stays in one (b,o) row
        int o = (int)((e / 7500) & 127);
        float sc = scale[o], sh = shift[o];
        uint2 v = *(const uint2*)(Y + e);
        float4 d;
        d.x = fmaxf(fmaf(bf2f((unsigned short)(v.x & 0xffffu)), sc, sh), 0.f);
        d.y = fmaxf(fmaf(bf2f((unsigned short)(v.x >> 16)),     sc, sh), 0.f);
        d.z = fmaxf(fmaf(bf2f((unsigned short)(v.y & 0xffffu)), sc, sh), 0.f);
        d.w = fmaxf(fmaf(bf2f((unsigned short)(v.y >> 16)),     sc, sh), 0.f);
        *(float4*)(out + e) = d;
    }
}

extern "C" void kernel_launch(void* const* d_in, const int* in_sizes, int n_in,
                              void* d_out, int out_size, void* d_ws, size_t ws_size,
                              hipStream_t stream) {
    const float* x     = (const float*)d_in[0];
    const float* A     = (const float*)d_in[1];
    const float* W     = (const float*)d_in[2];
    const float* Wr    = (const float*)d_in[3];
    const float* gamma = (const float*)d_in[5];
    const float* beta  = (const float*)d_in[6];
    float* out = (float*)d_out;
    char* wsb  = (char*)d_ws;
    if (ws_size < (size_t)WS_NEED2) return;   // proven >=198MB in prior rounds

    float*          apw = (float*)(wsb + WSB_APW);
    unsigned short* Wt  = (unsigned short*)(wsb + WSB_WT);
    float*          psc = (float*)(wsb + WSB_PSC);
    float*          psq = (float*)(wsb + WSB_PSQ);
    float*          scl = (float*)(wsb + WSB_SCL);
    float*          sft = (float*)(wsb + WSB_SFT);
    unsigned short* Y   = (unsigned short*)(wsb + WSB_Y);
    unsigned short* HR  = (unsigned short*)d_out;   // 245,760,000 B exact fit

    k_apow2<<<1, 256, 0, stream>>>(A, apw);
    k_wt<<<1, 256, 0, stream>>>(W, Wr, Wt);
    k_g1<<<dim3(59, 64), 512, 0, stream>>>(x, Wt, HR);
    k_pass2<<<NP2, 256, 0, stream>>>(HR, apw, Y, psc, psq);
    k_finalize3<<<128, 256, 0, stream>>>(psc, psq, gamma, beta, scl, sft);
    k_norm2<<<30000, 256, 0, stream>>>(Y, scl, sft, out);
}

// Round 7
// 292.754 us; speedup vs baseline: 5.7771x; 1.0534x over previous
//
#include <hip/hip_runtime.h>
#include <hip/hip_bf16.h>

// Problem constants
#define B_  64
#define C_  64
#define T_  300
#define V_  25
#define O_  128
#define TV  (T_*V_)     // 7500
#define BTV (B_*T_*V_)  // 480000
#define NPF 4800        // fuse blocks: 64 b x 75 tgroups (4 slabs each)

typedef __bf16 bf16x8 __attribute__((ext_vector_type(8)));
typedef float f32x4 __attribute__((ext_vector_type(4)));

// ---- ws layout (byte offsets); ws proven ~1GB, need < 128MB ----
#define WSB_APW   0ull           // padded A-powers [i*25+j][28] f32 = 22400 B (slot 22528)
#define WSB_WT    22528ull       // Wt[256][64] bf16 linear = 32768
#define WSB_PSC   55296ull       // [128][4800] f32 = 2,457,600
#define WSB_PSQ   2512896ull
#define WSB_SCL   4970496ull
#define WSB_SFT   4971008ull
#define WSB_Y     4971520ull     // [B*128][7500] bf16 = 122,880,000
#define WS_NEED2  127851520ull

static __device__ __forceinline__ unsigned short f2bf(float f) {
    unsigned int u = __float_as_uint(f);
    unsigned int r = (u + 0x7fffu + ((u >> 16) & 1u)) >> 16;
    return (unsigned short)r;
}
static __device__ __forceinline__ unsigned int pk2bf(float a, float b) {
    return (unsigned int)f2bf(a) | ((unsigned int)f2bf(b) << 16);
}
static __device__ __forceinline__ float bf2f(unsigned short u) {
    return __uint_as_float(((unsigned int)u) << 16);
}

// ---------------- A powers, padded layout apw[(i*25+j)*28 + k] = A^{i+1}[j,k] ----
__global__ __launch_bounds__(256) void k_apow2(const float* __restrict__ A,
                                               float* __restrict__ apw) {
    __shared__ float P[2][625];
    const int tid = threadIdx.x;
    for (int p = tid; p < 625; p += 256) P[0][p] = A[p];
    for (int idx = tid; idx < 5632; idx += 256) apw[idx] = 0.f;
    __syncthreads();
    int cur = 0;
    for (int i = 0; i < 8; i++) {
        if (i > 0) {
            for (int p = tid; p < 625; p += 256) {
                int r = p / 25, c2 = p - r * 25;
                float s = 0.f;
                #pragma unroll 5
                for (int j = 0; j < 25; j++) s = fmaf(P[cur][r*25 + j], A[j*25 + c2], s);
                P[cur ^ 1][p] = s;
            }
            __syncthreads();
            cur ^= 1;
        }
        for (int p = tid; p < 625; p += 256) {
            int r = p / 25, c2 = p - r * 25;
            apw[(i * 25 + r) * 28 + c2] = P[cur][p];
        }
        __syncthreads();
    }
}

// ---------------- Wt[oc][c] bf16 LINEAR; oc<128 -> W, else Wr ----------------
__global__ __launch_bounds__(256) void k_wt(const float* __restrict__ W,
                                            const float* __restrict__ Wr,
                                            unsigned short* __restrict__ Wt) {
    const int oc = threadIdx.x;
    const float* src = (oc < 128) ? (W + oc * 64) : (Wr + (oc - 128) * 64);
    unsigned short row[64];
    #pragma unroll
    for (int c = 0; c < 64; c++) row[c] = f2bf(src[c]);
    #pragma unroll
    for (int cc = 0; cc < 8; cc++)
        *(uint4*)(Wt + oc * 64 + cc * 8) = *(uint4*)(row + cc * 8);
}

// ---------------- fused: x->H (MFMA) -> graph-apply + residual + BN + Y ------
// block: 256 thr (4 waves), 4 slabs (b, t0..t0+3). 2 blocks/CU (73.6 KB LDS).
__global__ __launch_bounds__(256, 2) void k_fuse(const float* __restrict__ x,
                                                 const unsigned short* __restrict__ Wt,
                                                 const float* __restrict__ apw_g,
                                                 unsigned short* __restrict__ Y,
                                                 float* __restrict__ psc,
                                                 float* __restrict__ psq) {
    __shared__ __align__(16) unsigned short Hs[25600];  // 51.2KB H[100][256] swz; Yt overlay
    __shared__ __align__(16) float R_[5600];            // 22.4KB: As(16KB) -> Apw -> stats
    unsigned short* As = (unsigned short*)R_;
    const int blk = blockIdx.x;
    const int b = blk / 75, tg = blk - b * 75;
    const int tid = threadIdx.x, wv = tid >> 6, ln = tid & 63;
    const int wr = wv >> 1, wc = wv & 1;

    // preload B fragments from global Wt (L1/L2-resident); latency hides under staging
    bf16x8 bv[2][8];
    {
        const unsigned short* wb = Wt + (wc * 128 + (ln & 15)) * 64 + (ln >> 4) * 8;
        #pragma unroll
        for (int ks = 0; ks < 2; ks++)
            #pragma unroll
            for (int ni = 0; ni < 8; ni++)
                bv[ks][ni] = *(const bf16x8*)(wb + ni * 16 * 64 + ks * 32);
    }
    // zero As pad rows 100..127
    for (int w = tid; w < 896; w += 256) ((unsigned int*)As)[3200 + w] = 0u;
    // stage x -> As bf16 [row=tv_local][c], chunk-XOR swizzled by row&7
    for (int q = tid; q < 1600; q += 256) {
        int c = q / 25, e4 = q - c * 25;
        float4 f = *(const float4*)(x + ((size_t)(b * 64 + c)) * TV + tg * 100 + e4 * 4);
        float vv[4] = { f.x, f.y, f.z, f.w };
        #pragma unroll
        for (int u = 0; u < 4; u++) {
            int row = e4 * 4 + u;
            As[row * 64 + (((c >> 3) ^ (row & 7)) << 3) + (c & 7)] = f2bf(vv[u]);
        }
    }
    __syncthreads();

    // MFMA: H[128][256] = As(128x64) . Wt^T ; wave tile 64 rows x 128 cols
    f32x4 acc[4][8] = {};
    #pragma unroll
    for (int ks = 0; ks < 2; ks++) {
        bf16x8 af[4];
        #pragma unroll
        for (int mi = 0; mi < 4; mi++)
            af[mi] = *(const bf16x8*)(As + (wr * 64 + mi * 16 + (ln & 15)) * 64
                                         + (((ks * 4 + (ln >> 4)) ^ (ln & 7)) << 3));
        #pragma unroll
        for (int mi = 0; mi < 4; mi++)
            #pragma unroll
            for (int ni = 0; ni < 8; ni++)
                acc[mi][ni] = __builtin_amdgcn_mfma_f32_16x16x32_bf16(bv[ks][ni], af[mi], acc[mi][ni], 0, 0, 0);
    }
    // epilogue: H -> Hs bf16, chunk-swizzled (cc ^ row&7), rows < 100
    #pragma unroll
    for (int mi = 0; mi < 4; mi++) {
        int row = wr * 64 + mi * 16 + (ln & 15);
        if (row < 100) {
            #pragma unroll
            for (int ni = 0; ni < 8; ni++) {
                int co = wc * 128 + ni * 16 + (ln >> 4) * 4;
                int addr = row * 256 + (((co >> 3) ^ (row & 7)) << 3) + (co & 7);
                uint2 d;
                d.x = pk2bf(acc[mi][ni][0], acc[mi][ni][1]);
                d.y = pk2bf(acc[mi][ni][2], acc[mi][ni][3]);
                *(uint2*)(Hs + addr) = d;
            }
        }
    }
    __syncthreads();
    // As dead: copy padded A-powers (f32) into R_
    for (int q = tid; q < 1400; q += 256)
        ((float4*)R_)[q] = ((const float4*)apw_g)[q];
    __syncthreads();

    // phase 2: wave = slab s, lane = o-pair (o0 = 2*ln)
    const int s = wv;
    const int o0 = ln * 2;
    const float* Ai = R_ + (ln >> 3) * 700;      // branch i = o0>>4 = ln>>3
    float a0[25], a1[25];
    #pragma unroll
    for (int k = 0; k < 25; k++) { a0[k] = 0.f; a1[k] = 0.f; }
    for (int j = 0; j < 25; j++) {
        int hrow = s * 25 + j;
        unsigned int hh = *(const unsigned int*)(Hs + hrow * 256
                              + ((((ln >> 2)) ^ (hrow & 7)) << 3) + ((2 * ln) & 7));
        float h0 = bf2f((unsigned short)(hh & 0xffffu));
        float h1 = bf2f((unsigned short)(hh >> 16));
        const float4* ar = (const float4*)(Ai + j * 28);
        #pragma unroll
        for (int qd = 0; qd < 6; qd++) {
            float4 a = ar[qd];
            a0[qd*4+0] = fmaf(h0, a.x, a0[qd*4+0]); a1[qd*4+0] = fmaf(h1, a.x, a1[qd*4+0]);
            a0[qd*4+1] = fmaf(h0, a.y, a0[qd*4+1]); a1[qd*4+1] = fmaf(h1, a.y, a1[qd*4+1]);
            a0[qd*4+2] = fmaf(h0, a.z, a0[qd*4+2]); a1[qd*4+2] = fmaf(h1, a.z, a1[qd*4+2]);
            a0[qd*4+3] = fmaf(h0, a.w, a0[qd*4+3]); a1[qd*4+3] = fmaf(h1, a.w, a1[qd*4+3]);
        }
        float a24 = Ai[j * 28 + 24];
        a0[24] = fmaf(h0, a24, a0[24]); a1[24] = fmaf(h1, a24, a1[24]);
    }
    // residual: H[t,k][128+o]
    #pragma unroll
    for (int k = 0; k < 25; k++) {
        int hrow = s * 25 + k;
        unsigned int rr = *(const unsigned int*)(Hs + hrow * 256
                              + (((16 + (ln >> 2)) ^ (hrow & 7)) << 3) + ((2 * ln) & 7));
        a0[k] += bf2f((unsigned short)(rr & 0xffffu));
        a1[k] += bf2f((unsigned short)(rr >> 16));
    }
    // BN partials
    float s0 = 0.f, q0 = 0.f, s1 = 0.f, q1 = 0.f;
    #pragma unroll
    for (int k = 0; k < 25; k++) {
        s0 += a0[k]; q0 += a0[k] * a0[k];
        s1 += a1[k]; q1 += a1[k] * a1[k];
    }
    __syncthreads();     // all Hs + Apw reads done; overlay both regions
    // Yt overlay on Hs: [o][128] shorts, quad index swizzled by (o>>1)&15
    unsigned short* Yt = Hs;
    const int key = ln & 15;     // == (o0>>1)&15 == ((o0+1)>>1)&15
    #pragma unroll
    for (int k = 0; k < 25; k++) {
        int kidx = s * 25 + k, qd = kidx >> 2, wi = kidx & 3;
        Yt[o0 * 128 + ((qd ^ key) << 2) + wi]       = f2bf(a0[k]);
        Yt[(o0 + 1) * 128 + ((qd ^ key) << 2) + wi] = f2bf(a1[k]);
    }
    float* ssum = R_;            // Apw dead
    float* ssq  = R_ + 512;
    ssum[s * 128 + o0] = s0; ssum[s * 128 + o0 + 1] = s1;
    ssq [s * 128 + o0] = q0; ssq [s * 128 + o0 + 1] = q1;
    __syncthreads();
    if (tid < 128) {
        float S = ssum[tid] + ssum[128 + tid] + ssum[256 + tid] + ssum[384 + tid];
        float Q = ssq[tid]  + ssq[128 + tid]  + ssq[256 + tid]  + ssq[384 + tid];
        psc[(size_t)tid * NPF + blk] = S;
        psq[(size_t)tid * NPF + blk] = Q;
    }
    // Y[(b*128+o)][tg*100 + 0..99], coalesced uint2
    for (int idx = tid; idx < 3200; idx += 256) {
        int o = idx / 25, ch = idx - o * 25;
        uint2 d = *(const uint2*)(Yt + o * 128 + ((ch ^ ((o >> 1) & 15)) << 2));
        *(uint2*)(Y + ((size_t)(b * 128 + o)) * TV + tg * 100 + ch * 4) = d;
    }
}

// ---------------- finalize BN from per-(o,blk) partials ----------------
__global__ __launch_bounds__(256) void k_finalize3(const float* __restrict__ psc,
                                                   const float* __restrict__ psq,
                                                   const float* __restrict__ gamma,
                                                   const float* __restrict__ beta,
                                                   float* __restrict__ scale,
                                                   float* __restrict__ shift) {
    const int o = blockIdx.x, tid = threadIdx.x;
    float S = 0.f, Q = 0.f;
    for (int i = tid; i < NPF; i += 256) {
        S += psc[(size_t)o * NPF + i];
        Q += psq[(size_t)o * NPF + i];
    }
    #pragma unroll
    for (int m = 1; m < 64; m <<= 1) { S += __shfl_xor(S, m); Q += __shfl_xor(Q, m); }
    __shared__ float ls[4], lq[4];
    int w = tid >> 6;
    if ((tid & 63) == 0) { ls[w] = S; lq[w] = Q; }
    __syncthreads();
    if (tid == 0) {
        float St = ls[0] + ls[1] + ls[2] + ls[3];
        float Qt = lq[0] + lq[1] + lq[2] + lq[3];
        float inv = 1.f / (float)BTV;
        float mean = St * inv;
        float var = Qt * inv - mean * mean;
        float sc = gamma[o] / sqrtf(var + 1e-5f);
        scale[o] = sc;
        shift[o] = beta[o] - mean * sc;
    }
}

// ---------------- norm: Y bf16 (final layout) -> out f32, fully linear ----------
__global__ __launch_bounds__(256) void k_norm2(const unsigned short* __restrict__ Y,
                                               const float* __restrict__ scale,
                                               const float* __restrict__ shift,
                                               float* __restrict__ out) {
    size_t e0 = ((size_t)blockIdx.x * 256 + threadIdx.x) * 8;
    #pragma unroll
    for (int g = 0; g < 2; g++) {
        size_t e = e0 + (size_t)g * 4;
        int o = (int)((e / 7500) & 127);
        float sc = scale[o], sh = shift[o];
        uint2 v = *(const uint2*)(Y + e);
        float4 d;
        d.x = fmaxf(fmaf(bf2f((unsigned short)(v.x & 0xffffu)), sc, sh), 0.f);
        d.y = fmaxf(fmaf(bf2f((unsigned short)(v.x >> 16)),     sc, sh), 0.f);
        d.z = fmaxf(fmaf(bf2f((unsigned short)(v.y & 0xffffu)), sc, sh), 0.f);
        d.w = fmaxf(fmaf(bf2f((unsigned short)(v.y >> 16)),     sc, sh), 0.f);
        *(float4*)(out + e) = d;
    }
}

extern "C" void kernel_launch(void* const* d_in, const int* in_sizes, int n_in,
                              void* d_out, int out_size, void* d_ws, size_t ws_size,
                              hipStream_t stream) {
    const float* x     = (const float*)d_in[0];
    const float* A     = (const float*)d_in[1];
    const float* W     = (const float*)d_in[2];
    const float* Wr    = (const float*)d_in[3];
    const float* gamma = (const float*)d_in[5];
    const float* beta  = (const float*)d_in[6];
    float* out = (float*)d_out;
    char* wsb  = (char*)d_ws;
    if (ws_size < (size_t)WS_NEED2) return;

    float*          apw = (float*)(wsb + WSB_APW);
    unsigned short* Wt  = (unsigned short*)(wsb + WSB_WT);
    float*          psc = (float*)(wsb + WSB_PSC);
    float*          psq = (float*)(wsb + WSB_PSQ);
    float*          scl = (float*)(wsb + WSB_SCL);
    float*          sft = (float*)(wsb + WSB_SFT);
    unsigned short* Y   = (unsigned short*)(wsb + WSB_Y);

    k_apow2<<<1, 256, 0, stream>>>(A, apw);
    k_wt<<<1, 256, 0, stream>>>(W, Wr, Wt);
    k_fuse<<<NPF, 256, 0, stream>>>(x, Wt, apw, Y, psc, psq);
    k_finalize3<<<128, 256, 0, stream>>>(psc, psq, gamma, beta, scl, sft);
    k_norm2<<<30000, 256, 0, stream>>>(Y, scl, sft, out);
}